// Round 4
// baseline (880.536 us; speedup 1.0000x reference)
//
#include <hip/hip_runtime.h>
#include <hip/hip_bf16.h>

#define HID 128

using bf16x8 = __attribute__((ext_vector_type(8))) short;
using f32x4  = __attribute__((ext_vector_type(4))) float;

__device__ inline float bf2f(unsigned int u16) {
    union { float f; unsigned int i; } v; v.i = u16 << 16; return v.f;
}
__device__ inline unsigned short f2bf(float f) {
    __hip_bfloat16 h = __float2bfloat16(f);        // RNE
    return *reinterpret_cast<unsigned short*>(&h);
}

// ---------------- CSR build ----------------

__global__ void zero_i32(int* __restrict__ p, int n) {
    int i = blockIdx.x * blockDim.x + threadIdx.x;
    if (i < n) p[i] = 0;
}

__global__ void count_deg(const int* __restrict__ dst, int* __restrict__ deg, int E) {
    int e = blockIdx.x * blockDim.x + threadIdx.x;
    if (e < E) atomicAdd(&deg[dst[e]], 1);
}

__global__ __launch_bounds__(256) void block_sums(const int* __restrict__ deg,
                                                  int* __restrict__ bsum, int n) {
    __shared__ int red[256];
    int t = threadIdx.x;
    int i = blockIdx.x * 256 + t;
    red[t] = (i < n) ? deg[i] : 0;
    __syncthreads();
    for (int off = 128; off > 0; off >>= 1) {
        if (t < off) red[t] += red[t + off];
        __syncthreads();
    }
    if (t == 0) bsum[blockIdx.x] = red[0];
}

__global__ __launch_bounds__(1024) void scan_bsums(const int* __restrict__ bsum,
                                                   int* __restrict__ bstart, int nb) {
    __shared__ int s[1024];
    int t = threadIdx.x;
    s[t] = (t < nb) ? bsum[t] : 0;
    __syncthreads();
    for (int off = 1; off < 1024; off <<= 1) {
        int v = (t >= off) ? s[t - off] : 0;
        __syncthreads();
        s[t] += v;
        __syncthreads();
    }
    if (t < nb) bstart[t] = (t == 0) ? 0 : s[t - 1];
}

__global__ __launch_bounds__(256) void scan_within(const int* __restrict__ deg,
                                                   const int* __restrict__ bstart,
                                                   int* __restrict__ row_ptr,
                                                   int* __restrict__ pos, int n) {
    __shared__ int s[256];
    int b = blockIdx.x, t = threadIdx.x;
    int i = b * 256 + t;
    int v = (i < n) ? deg[i] : 0;
    s[t] = v;
    __syncthreads();
    for (int off = 1; off < 256; off <<= 1) {
        int u = (t >= off) ? s[t - off] : 0;
        __syncthreads();
        s[t] += u;
        __syncthreads();
    }
    if (i < n) {
        int excl = bstart[b] + s[t] - v;
        row_ptr[i] = excl;
        pos[i] = excl;
        if (i == n - 1) row_ptr[n] = bstart[b] + s[t];
    }
}

__global__ void fill_csr(const int* __restrict__ src, const int* __restrict__ dst,
                         int* __restrict__ pos, int* __restrict__ csr_src, int E) {
    int e = blockIdx.x * blockDim.x + threadIdx.x;
    if (e < E) {
        int p = atomicAdd(&pos[dst[e]], 1);
        csr_src[p] = src[e];
    }
}

__global__ void graph_starts(const int* __restrict__ batch, int* __restrict__ gstart,
                             int n, int G) {
    int g = blockIdx.x * blockDim.x + threadIdx.x;
    if (g > G) return;
    int lo = 0, hi = n;
    while (lo < hi) { int m = (lo + hi) >> 1; if (batch[m] < g) lo = m + 1; else hi = m; }
    gstart[g] = lo;
}

// ---------------- conversions ----------------

__global__ void f32_to_bf16_vec(const float* __restrict__ in,
                                unsigned short* __restrict__ out, int n8) {
    int i = blockIdx.x * blockDim.x + threadIdx.x;
    if (i >= n8) return;
    const float4* in4 = (const float4*)in;
    float4 a = in4[i * 2], b = in4[i * 2 + 1];
    uint4 o;
    o.x = f2bf(a.x) | ((unsigned)f2bf(a.y) << 16);
    o.y = f2bf(a.z) | ((unsigned)f2bf(a.w) << 16);
    o.z = f2bf(b.x) | ((unsigned)f2bf(b.y) << 16);
    o.w = f2bf(b.z) | ((unsigned)f2bf(b.w) << 16);
    ((uint4*)out)[i] = o;
}

// W[mat][k][c] fp32 -> Wt[mat][c][k] bf16. tid -> (mat, c, k)
__global__ void transpose_kc(const float* __restrict__ W, unsigned short* __restrict__ Wt,
                             int K, int C, int total) {
    int tid = blockIdx.x * blockDim.x + threadIdx.x;
    if (tid >= total) return;
    int kc = K * C;
    int mat = tid / kc;
    int rem = tid - mat * kc;
    int c = rem / K;
    int k = rem - c * K;
    Wt[tid] = f2bf(W[(size_t)mat * kc + (size_t)k * C + c]);
}

// ---------------- fused GIN layer ----------------
// one block = 128 node rows: gather z=h+sum(h[src]) -> LDS (swizzled bf16 tile),
// GEMM1 (+b1, relu) -> LDS, GEMM2 (+b2 [,+xres]) -> h_out bf16 [, xres fp32]
template <bool ODD>
__global__ __launch_bounds__(256) void fused_layer(const unsigned short* __restrict__ h,
                                                   const int* __restrict__ row_ptr,
                                                   const int* __restrict__ csr_src,
                                                   const unsigned short* __restrict__ Wt1,
                                                   const float* __restrict__ b1,
                                                   const unsigned short* __restrict__ Wt2,
                                                   const float* __restrict__ b2,
                                                   float* __restrict__ xres,
                                                   unsigned short* __restrict__ h_out,
                                                   int N) {
    __shared__ __align__(16) char lds[128 * 256];   // 32 KB bf16 [128 rows][128 cols], XOR-swizzled
    int t = threadIdx.x;

    // ---- gather phase: 16 lanes/node (16 B each), 16 nodes per pass ----
    {
        int lane16 = t & 15, nsub = t >> 4;
        const uint4* h4 = (const uint4*)h;
        for (int rc = 0; rc < 8; rc++) {
            int ln = rc * 16 + nsub;                 // local row 0..127
            int node = blockIdx.x * 128 + ln;
            uint4 o = {0u, 0u, 0u, 0u};
            if (node < N) {
                uint4 u = h4[(size_t)node * 16 + lane16];
                float s0 = bf2f(u.x & 0xffff), s1 = bf2f(u.x >> 16);
                float s2 = bf2f(u.y & 0xffff), s3 = bf2f(u.y >> 16);
                float s4 = bf2f(u.z & 0xffff), s5 = bf2f(u.z >> 16);
                float s6 = bf2f(u.w & 0xffff), s7 = bf2f(u.w >> 16);
                int e0 = row_ptr[node], e1 = row_ptr[node + 1];
                int e = e0;
                for (; e + 1 < e1; e += 2) {         // unroll 2 for load ILP
                    int sa = csr_src[e], sb = csr_src[e + 1];
                    uint4 va = h4[(size_t)sa * 16 + lane16];
                    uint4 vb = h4[(size_t)sb * 16 + lane16];
                    s0 += bf2f(va.x & 0xffff); s1 += bf2f(va.x >> 16);
                    s2 += bf2f(va.y & 0xffff); s3 += bf2f(va.y >> 16);
                    s4 += bf2f(va.z & 0xffff); s5 += bf2f(va.z >> 16);
                    s6 += bf2f(va.w & 0xffff); s7 += bf2f(va.w >> 16);
                    s0 += bf2f(vb.x & 0xffff); s1 += bf2f(vb.x >> 16);
                    s2 += bf2f(vb.y & 0xffff); s3 += bf2f(vb.y >> 16);
                    s4 += bf2f(vb.z & 0xffff); s5 += bf2f(vb.z >> 16);
                    s6 += bf2f(vb.w & 0xffff); s7 += bf2f(vb.w >> 16);
                }
                if (e < e1) {
                    uint4 va = h4[(size_t)csr_src[e] * 16 + lane16];
                    s0 += bf2f(va.x & 0xffff); s1 += bf2f(va.x >> 16);
                    s2 += bf2f(va.y & 0xffff); s3 += bf2f(va.y >> 16);
                    s4 += bf2f(va.z & 0xffff); s5 += bf2f(va.z >> 16);
                    s6 += bf2f(va.w & 0xffff); s7 += bf2f(va.w >> 16);
                }
                o.x = f2bf(s0) | ((unsigned)f2bf(s1) << 16);
                o.y = f2bf(s2) | ((unsigned)f2bf(s3) << 16);
                o.z = f2bf(s4) | ((unsigned)f2bf(s5) << 16);
                o.w = f2bf(s6) | ((unsigned)f2bf(s7) << 16);
            }
            int addr = ln * 256 + ((lane16 * 16) ^ ((ln & 7) << 4));
            *(uint4*)(lds + addr) = o;
        }
    }
    __syncthreads();

    int wave = t >> 6, lane = t & 63, l15 = lane & 15, l4 = lane >> 4;
    int wrow = wave * 32;
    f32x4 acc[2][8];
#pragma unroll
    for (int rt = 0; rt < 2; rt++)
#pragma unroll
        for (int ct = 0; ct < 8; ct++) acc[rt][ct] = (f32x4){0.f, 0.f, 0.f, 0.f};

    // ---- GEMM1: z @ W1 ----
#pragma unroll
    for (int kk = 0; kk < 4; kk++) {
        int k0 = kk * 32 + l4 * 8;
        int r0 = wrow + l15, r1 = r0 + 16;
        bf16x8 a0 = *(const bf16x8*)(lds + r0 * 256 + ((k0 * 2) ^ ((r0 & 7) << 4)));
        bf16x8 a1 = *(const bf16x8*)(lds + r1 * 256 + ((k0 * 2) ^ ((r1 & 7) << 4)));
#pragma unroll
        for (int ct = 0; ct < 8; ct++) {
            bf16x8 b = *(const bf16x8*)&Wt1[(size_t)(ct * 16 + l15) * HID + k0];
            acc[0][ct] = __builtin_amdgcn_mfma_f32_16x16x32_bf16(a0, b, acc[0][ct], 0, 0, 0);
            acc[1][ct] = __builtin_amdgcn_mfma_f32_16x16x32_bf16(a1, b, acc[1][ct], 0, 0, 0);
        }
    }
    __syncthreads();   // all zt reads done before overwrite

    // ---- epilogue1: relu(acc + b1) -> LDS ----
#pragma unroll
    for (int ct = 0; ct < 8; ct++) {
        int col = ct * 16 + l15;
        float bc = b1[col];
#pragma unroll
        for (int rt = 0; rt < 2; rt++)
#pragma unroll
            for (int j = 0; j < 4; j++) {
                int r = wrow + rt * 16 + l4 * 4 + j;
                float v = fmaxf(acc[rt][ct][j] + bc, 0.f);
                *(unsigned short*)(lds + r * 256 + ((col * 2) ^ ((r & 7) << 4))) = f2bf(v);
            }
    }
    __syncthreads();

    // ---- GEMM2: t @ W2 ----
#pragma unroll
    for (int rt = 0; rt < 2; rt++)
#pragma unroll
        for (int ct = 0; ct < 8; ct++) acc[rt][ct] = (f32x4){0.f, 0.f, 0.f, 0.f};
#pragma unroll
    for (int kk = 0; kk < 4; kk++) {
        int k0 = kk * 32 + l4 * 8;
        int r0 = wrow + l15, r1 = r0 + 16;
        bf16x8 a0 = *(const bf16x8*)(lds + r0 * 256 + ((k0 * 2) ^ ((r0 & 7) << 4)));
        bf16x8 a1 = *(const bf16x8*)(lds + r1 * 256 + ((k0 * 2) ^ ((r1 & 7) << 4)));
#pragma unroll
        for (int ct = 0; ct < 8; ct++) {
            bf16x8 b = *(const bf16x8*)&Wt2[(size_t)(ct * 16 + l15) * HID + k0];
            acc[0][ct] = __builtin_amdgcn_mfma_f32_16x16x32_bf16(a0, b, acc[0][ct], 0, 0, 0);
            acc[1][ct] = __builtin_amdgcn_mfma_f32_16x16x32_bf16(a1, b, acc[1][ct], 0, 0, 0);
        }
    }

    // ---- epilogue2: +b2 [,+xres], h_out = relu ----
#pragma unroll
    for (int ct = 0; ct < 8; ct++) {
        int col = ct * 16 + l15;
        float bc = b2[col];
#pragma unroll
        for (int rt = 0; rt < 2; rt++)
#pragma unroll
            for (int j = 0; j < 4; j++) {
                int r = wrow + rt * 16 + l4 * 4 + j;
                int rg = blockIdx.x * 128 + r;
                if (rg < N) {
                    float v = acc[rt][ct][j] + bc;
                    if (ODD) {
                        v += xres[(size_t)rg * HID + col];
                        xres[(size_t)rg * HID + col] = v;
                    }
                    h_out[(size_t)rg * HID + col] = f2bf(fmaxf(v, 0.f));
                }
            }
    }
}

// ---------------- pre linear (MFMA, global in) ----------------
__global__ __launch_bounds__(256) void linear_pre(const unsigned short* __restrict__ in,
                                                  const unsigned short* __restrict__ Wt,
                                                  const float* __restrict__ bias,
                                                  unsigned short* __restrict__ out,
                                                  float* __restrict__ pre_out, int M) {
    int tid = threadIdx.x;
    int wave = tid >> 6, lane = tid & 63;
    int l15 = lane & 15, l4 = lane >> 4;
    int rowbase = blockIdx.x * 128 + wave * 32;
    f32x4 acc[2][8];
#pragma unroll
    for (int rt = 0; rt < 2; rt++)
#pragma unroll
        for (int ct = 0; ct < 8; ct++) acc[rt][ct] = (f32x4){0.f, 0.f, 0.f, 0.f};
    int r0 = min(rowbase + l15, M - 1);
    int r1 = min(rowbase + 16 + l15, M - 1);
#pragma unroll
    for (int kk = 0; kk < 4; kk++) {
        int k0 = kk * 32 + l4 * 8;
        bf16x8 a0 = *(const bf16x8*)&in[(size_t)r0 * HID + k0];
        bf16x8 a1 = *(const bf16x8*)&in[(size_t)r1 * HID + k0];
#pragma unroll
        for (int ct = 0; ct < 8; ct++) {
            bf16x8 b = *(const bf16x8*)&Wt[(size_t)(ct * 16 + l15) * HID + k0];
            acc[0][ct] = __builtin_amdgcn_mfma_f32_16x16x32_bf16(a0, b, acc[0][ct], 0, 0, 0);
            acc[1][ct] = __builtin_amdgcn_mfma_f32_16x16x32_bf16(a1, b, acc[1][ct], 0, 0, 0);
        }
    }
#pragma unroll
    for (int ct = 0; ct < 8; ct++) {
        int col = ct * 16 + l15;
        float bc = bias[col];
#pragma unroll
        for (int rt = 0; rt < 2; rt++)
#pragma unroll
            for (int j = 0; j < 4; j++) {
                int r = rowbase + rt * 16 + l4 * 4 + j;
                if (r < M) {
                    float v = acc[rt][ct][j] + bc;
                    pre_out[(size_t)r * HID + col] = v;     // xres (fp32, pre-activation == value, no relu on pre)
                    out[(size_t)r * HID + col] = f2bf(v);
                }
            }
    }
}

// ---------------- pooling (bf16 in, bf16 out, fp32 accum) ----------------
__global__ __launch_bounds__(1024) void pool_kernel(const unsigned short* __restrict__ h,
                                                    const int* __restrict__ gstart,
                                                    unsigned short* __restrict__ pooled,
                                                    int off, int EMB) {
    int g = blockIdx.x;
    int c = threadIdx.x & 127;
    int rg = threadIdx.x >> 7;  // 0..7
    __shared__ float part[8][HID];
    int n0 = gstart[g], n1 = gstart[g + 1];
    float s = 0.f;
    for (int n = n0 + rg; n < n1; n += 8) s += bf2f(h[(size_t)n * HID + c]);
    part[rg][c] = s;
    __syncthreads();
    if (rg == 0) {
        float tsum = 0.f;
#pragma unroll
        for (int r = 0; r < 8; r++) tsum += part[r][c];
        pooled[(size_t)g * EMB + off + c] = f2bf(tsum);
    }
}

// ---------------- post MLP via MFMA: out = relu(pooled@w1+b1)@w2+b2 ----------------
// single block, 4 waves x 32 rows = 128 graphs; K1=EMB, K2=128
__global__ __launch_bounds__(256) void post_mfma(const unsigned short* __restrict__ pooled,
                                                 const unsigned short* __restrict__ w1t,
                                                 const float* __restrict__ b1,
                                                 const unsigned short* __restrict__ w2t,
                                                 const float* __restrict__ b2,
                                                 float* __restrict__ out, int EMB) {
    __shared__ __align__(16) char lds[128 * 256];
    int t = threadIdx.x;
    int wave = t >> 6, lane = t & 63, l15 = lane & 15, l4 = lane >> 4;
    int wrow = wave * 32;
    f32x4 acc[2][8];
#pragma unroll
    for (int rt = 0; rt < 2; rt++)
#pragma unroll
        for (int ct = 0; ct < 8; ct++) acc[rt][ct] = (f32x4){0.f, 0.f, 0.f, 0.f};
    int r0 = wrow + l15, r1 = r0 + 16;
#pragma unroll 4
    for (int kk = 0; kk < EMB / 32; kk++) {
        int k0 = kk * 32 + l4 * 8;
        bf16x8 a0 = *(const bf16x8*)&pooled[(size_t)r0 * EMB + k0];
        bf16x8 a1 = *(const bf16x8*)&pooled[(size_t)r1 * EMB + k0];
#pragma unroll
        for (int ct = 0; ct < 8; ct++) {
            bf16x8 b = *(const bf16x8*)&w1t[(size_t)(ct * 16 + l15) * EMB + k0];
            acc[0][ct] = __builtin_amdgcn_mfma_f32_16x16x32_bf16(a0, b, acc[0][ct], 0, 0, 0);
            acc[1][ct] = __builtin_amdgcn_mfma_f32_16x16x32_bf16(a1, b, acc[1][ct], 0, 0, 0);
        }
    }
    // y1 = relu(acc+b1) -> LDS
#pragma unroll
    for (int ct = 0; ct < 8; ct++) {
        int col = ct * 16 + l15;
        float bc = b1[col];
#pragma unroll
        for (int rt = 0; rt < 2; rt++)
#pragma unroll
            for (int j = 0; j < 4; j++) {
                int r = wrow + rt * 16 + l4 * 4 + j;
                float v = fmaxf(acc[rt][ct][j] + bc, 0.f);
                *(unsigned short*)(lds + r * 256 + ((col * 2) ^ ((r & 7) << 4))) = f2bf(v);
            }
    }
    __syncthreads();
#pragma unroll
    for (int rt = 0; rt < 2; rt++)
#pragma unroll
        for (int ct = 0; ct < 8; ct++) acc[rt][ct] = (f32x4){0.f, 0.f, 0.f, 0.f};
#pragma unroll
    for (int kk = 0; kk < 4; kk++) {
        int k0 = kk * 32 + l4 * 8;
        bf16x8 a0 = *(const bf16x8*)(lds + r0 * 256 + ((k0 * 2) ^ ((r0 & 7) << 4)));
        bf16x8 a1 = *(const bf16x8*)(lds + r1 * 256 + ((k0 * 2) ^ ((r1 & 7) << 4)));
#pragma unroll
        for (int ct = 0; ct < 8; ct++) {
            bf16x8 b = *(const bf16x8*)&w2t[(size_t)(ct * 16 + l15) * HID + k0];
            acc[0][ct] = __builtin_amdgcn_mfma_f32_16x16x32_bf16(a0, b, acc[0][ct], 0, 0, 0);
            acc[1][ct] = __builtin_amdgcn_mfma_f32_16x16x32_bf16(a1, b, acc[1][ct], 0, 0, 0);
        }
    }
#pragma unroll
    for (int ct = 0; ct < 8; ct++) {
        int col = ct * 16 + l15;
        float bc = b2[col];
#pragma unroll
        for (int rt = 0; rt < 2; rt++)
#pragma unroll
            for (int j = 0; j < 4; j++) {
                int r = wrow + rt * 16 + l4 * 4 + j;
                out[(size_t)r * HID + col] = acc[rt][ct][j] + bc;
            }
    }
}

// ---------------- launch ----------------

extern "C" void kernel_launch(void* const* d_in, const int* in_sizes, int n_in,
                              void* d_out, int out_size, void* d_ws, size_t ws_size,
                              hipStream_t stream) {
    const float* x       = (const float*)d_in[0];
    const int* edge_index= (const int*)d_in[1];
    const int* batch     = (const int*)d_in[2];
    const float* pre_w   = (const float*)d_in[3];
    const float* pre_b   = (const float*)d_in[4];
    const float* conv_w1 = (const float*)d_in[5];
    const float* conv_b1 = (const float*)d_in[6];
    const float* conv_w2 = (const float*)d_in[7];
    const float* conv_b2 = (const float*)d_in[8];
    const float* post_w1 = (const float*)d_in[9];
    const float* post_b1 = (const float*)d_in[10];
    const float* post_w2 = (const float*)d_in[11];
    const float* post_b2 = (const float*)d_in[12];
    float* outp = (float*)d_out;

    int N = in_sizes[0] / HID;
    int E = in_sizes[1] / 2;
    int L = in_sizes[5] / (HID * HID);
    int G = out_size / HID;
    int EMB = (L + 1) * HID;

    const int* src = edge_index;
    const int* dst = edge_index + E;

    char* w = (char*)d_ws;
    auto alloc = [&](size_t bytes) -> char* {
        char* p = w;
        w += (bytes + 255) & ~(size_t)255;
        return p;
    };
    unsigned short* x_bf  = (unsigned short*)alloc((size_t)N * HID * 2);
    unsigned short* hA    = (unsigned short*)alloc((size_t)N * HID * 2);
    unsigned short* hB    = (unsigned short*)alloc((size_t)N * HID * 2);
    float* xres   = (float*)alloc((size_t)N * HID * 4);
    unsigned short* pooled = (unsigned short*)alloc((size_t)G * EMB * 2);
    unsigned short* Wt_pre = (unsigned short*)alloc((size_t)HID * HID * 2);
    unsigned short* Wt_c1  = (unsigned short*)alloc((size_t)L * HID * HID * 2);
    unsigned short* Wt_c2  = (unsigned short*)alloc((size_t)L * HID * HID * 2);
    unsigned short* w1t    = (unsigned short*)alloc((size_t)EMB * HID * 2);
    unsigned short* w2t    = (unsigned short*)alloc((size_t)HID * HID * 2);
    int* deg      = (int*)alloc((size_t)(N + 1) * 4);
    int* row_ptr  = (int*)alloc((size_t)(N + 1) * 4);
    int* pos      = (int*)alloc((size_t)(N + 1) * 4);
    int* bsum     = (int*)alloc((size_t)1024 * 4);
    int* bstart   = (int*)alloc((size_t)1024 * 4);
    int* csr_src  = (int*)alloc((size_t)E * 4);
    int* gstart   = (int*)alloc((size_t)(G + 1) * 4);
    (void)ws_size; (void)n_in;

    int eb = (E + 255) / 256;
    int nb = (N + 255) / 256;

    // CSR by dst
    zero_i32<<<nb, 256, 0, stream>>>(deg, N);
    count_deg<<<eb, 256, 0, stream>>>(dst, deg, E);
    block_sums<<<nb, 256, 0, stream>>>(deg, bsum, N);
    scan_bsums<<<1, 1024, 0, stream>>>(bsum, bstart, nb);
    scan_within<<<nb, 256, 0, stream>>>(deg, bstart, row_ptr, pos, N);
    fill_csr<<<eb, 256, 0, stream>>>(src, dst, pos, csr_src, E);
    graph_starts<<<1, 256, 0, stream>>>(batch, gstart, N, G);

    // conversions / transposes
    f32_to_bf16_vec<<<(N * HID / 8 + 255) / 256, 256, 0, stream>>>(x, x_bf, N * HID / 8);
    transpose_kc<<<(HID * HID + 255) / 256, 256, 0, stream>>>(pre_w, Wt_pre, HID, HID, HID * HID);
    transpose_kc<<<(L * HID * HID + 255) / 256, 256, 0, stream>>>(conv_w1, Wt_c1, HID, HID, L * HID * HID);
    transpose_kc<<<(L * HID * HID + 255) / 256, 256, 0, stream>>>(conv_w2, Wt_c2, HID, HID, L * HID * HID);
    transpose_kc<<<(EMB * HID + 255) / 256, 256, 0, stream>>>(post_w1, w1t, EMB, HID, EMB * HID);
    transpose_kc<<<(HID * HID + 255) / 256, 256, 0, stream>>>(post_w2, w2t, HID, HID, HID * HID);

    int gb = (N + 127) / 128;

    // pre linear: h = x@pre_w + pre_b ; xres = h (fp32)
    linear_pre<<<gb, 256, 0, stream>>>(x_bf, Wt_pre, pre_b, hA, xres, N);
    pool_kernel<<<G, 1024, 0, stream>>>(hA, gstart, pooled, 0, EMB);

    unsigned short* hcur = hA;
    unsigned short* hnxt = hB;
    for (int i = 0; i < L; i++) {
        if (i & 1) {
            fused_layer<true><<<gb, 256, 0, stream>>>(
                hcur, row_ptr, csr_src,
                Wt_c1 + (size_t)i * HID * HID, conv_b1 + i * HID,
                Wt_c2 + (size_t)i * HID * HID, conv_b2 + i * HID,
                xres, hnxt, N);
        } else {
            fused_layer<false><<<gb, 256, 0, stream>>>(
                hcur, row_ptr, csr_src,
                Wt_c1 + (size_t)i * HID * HID, conv_b1 + i * HID,
                Wt_c2 + (size_t)i * HID * HID, conv_b2 + i * HID,
                xres, hnxt, N);
        }
        pool_kernel<<<G, 1024, 0, stream>>>(hnxt, gstart, pooled, (i + 1) * HID, EMB);
        unsigned short* tmp = hcur; hcur = hnxt; hnxt = tmp;
    }

    post_mfma<<<1, 256, 0, stream>>>(pooled, w1t, post_b1, w2t, post_b2, outp, EMB);
}

// Round 5
// 685.698 us; speedup vs baseline: 1.2841x; 1.2841x over previous
//
#include <hip/hip_runtime.h>
#include <hip/hip_bf16.h>

#define HID 128

using bf16x8 = __attribute__((ext_vector_type(8))) short;
using f32x4  = __attribute__((ext_vector_type(4))) float;

__device__ inline float bf2f(unsigned int u16) {
    union { float f; unsigned int i; } v; v.i = u16 << 16; return v.f;
}
__device__ inline unsigned short f2bf(float f) {
    __hip_bfloat16 h = __float2bfloat16(f);        // RNE
    return *reinterpret_cast<unsigned short*>(&h);
}

// ---------------- CSR build ----------------

__global__ void zero_i32(int* __restrict__ p, int n) {
    int i = blockIdx.x * blockDim.x + threadIdx.x;
    if (i < n) p[i] = 0;
}

__global__ void count_deg(const int* __restrict__ dst, int* __restrict__ deg, int E) {
    int e = blockIdx.x * blockDim.x + threadIdx.x;
    if (e < E) atomicAdd(&deg[dst[e]], 1);
}

__global__ __launch_bounds__(256) void block_sums(const int* __restrict__ deg,
                                                  int* __restrict__ bsum, int n) {
    __shared__ int red[256];
    int t = threadIdx.x;
    int i = blockIdx.x * 256 + t;
    red[t] = (i < n) ? deg[i] : 0;
    __syncthreads();
    for (int off = 128; off > 0; off >>= 1) {
        if (t < off) red[t] += red[t + off];
        __syncthreads();
    }
    if (t == 0) bsum[blockIdx.x] = red[0];
}

__global__ __launch_bounds__(1024) void scan_bsums(const int* __restrict__ bsum,
                                                   int* __restrict__ bstart, int nb) {
    __shared__ int s[1024];
    int t = threadIdx.x;
    s[t] = (t < nb) ? bsum[t] : 0;
    __syncthreads();
    for (int off = 1; off < 1024; off <<= 1) {
        int v = (t >= off) ? s[t - off] : 0;
        __syncthreads();
        s[t] += v;
        __syncthreads();
    }
    if (t < nb) bstart[t] = (t == 0) ? 0 : s[t - 1];
}

__global__ __launch_bounds__(256) void scan_within(const int* __restrict__ deg,
                                                   const int* __restrict__ bstart,
                                                   int* __restrict__ row_ptr,
                                                   int* __restrict__ pos, int n) {
    __shared__ int s[256];
    int b = blockIdx.x, t = threadIdx.x;
    int i = b * 256 + t;
    int v = (i < n) ? deg[i] : 0;
    s[t] = v;
    __syncthreads();
    for (int off = 1; off < 256; off <<= 1) {
        int u = (t >= off) ? s[t - off] : 0;
        __syncthreads();
        s[t] += u;
        __syncthreads();
    }
    if (i < n) {
        int excl = bstart[b] + s[t] - v;
        row_ptr[i] = excl;
        pos[i] = excl;
        if (i == n - 1) row_ptr[n] = bstart[b] + s[t];
    }
}

__global__ void fill_csr(const int* __restrict__ src, const int* __restrict__ dst,
                         int* __restrict__ pos, int* __restrict__ csr_src, int E) {
    int e = blockIdx.x * blockDim.x + threadIdx.x;
    if (e < E) {
        int p = atomicAdd(&pos[dst[e]], 1);
        csr_src[p] = src[e];
    }
}

__global__ void graph_starts(const int* __restrict__ batch, int* __restrict__ gstart,
                             int n, int G) {
    int g = blockIdx.x * blockDim.x + threadIdx.x;
    if (g > G) return;
    int lo = 0, hi = n;
    while (lo < hi) { int m = (lo + hi) >> 1; if (batch[m] < g) lo = m + 1; else hi = m; }
    gstart[g] = lo;
}

// ---------------- conversions ----------------

__global__ void f32_to_bf16_vec(const float* __restrict__ in,
                                unsigned short* __restrict__ out, int n8) {
    int i = blockIdx.x * blockDim.x + threadIdx.x;
    if (i >= n8) return;
    const float4* in4 = (const float4*)in;
    float4 a = in4[i * 2], b = in4[i * 2 + 1];
    uint4 o;
    o.x = f2bf(a.x) | ((unsigned)f2bf(a.y) << 16);
    o.y = f2bf(a.z) | ((unsigned)f2bf(a.w) << 16);
    o.z = f2bf(b.x) | ((unsigned)f2bf(b.y) << 16);
    o.w = f2bf(b.z) | ((unsigned)f2bf(b.w) << 16);
    ((uint4*)out)[i] = o;
}

// W[mat][k][c] fp32 -> Wt[mat][c][k] bf16
__global__ void transpose_kc(const float* __restrict__ W, unsigned short* __restrict__ Wt,
                             int K, int C, int total) {
    int tid = blockIdx.x * blockDim.x + threadIdx.x;
    if (tid >= total) return;
    int kc = K * C;
    int mat = tid / kc;
    int rem = tid - mat * kc;
    int c = rem / K;
    int k = rem - c * K;
    Wt[tid] = f2bf(W[(size_t)mat * kc + (size_t)k * C + c]);
}

// ---------------- aggregation: z = h + sum_in-edges h[src] ----------------
// 16 lanes/node (16B each), 16 nodes / 256-thr block, 3125 blocks: max parallelism

__global__ __launch_bounds__(256) void agg_kernel(const unsigned short* __restrict__ h,
                                                  const int* __restrict__ row_ptr,
                                                  const int* __restrict__ csr_src,
                                                  unsigned short* __restrict__ z, int N) {
    int node = blockIdx.x * 16 + (threadIdx.x >> 4);
    int lane = threadIdx.x & 15;
    if (node >= N) return;
    const uint4* h4 = (const uint4*)h;
    uint4 u = h4[(size_t)node * 16 + lane];
    float s0 = bf2f(u.x & 0xffff), s1 = bf2f(u.x >> 16);
    float s2 = bf2f(u.y & 0xffff), s3 = bf2f(u.y >> 16);
    float s4 = bf2f(u.z & 0xffff), s5 = bf2f(u.z >> 16);
    float s6 = bf2f(u.w & 0xffff), s7 = bf2f(u.w >> 16);
    int e0 = row_ptr[node], e1 = row_ptr[node + 1];
    int e = e0;
    for (; e + 1 < e1; e += 2) {
        int sa = csr_src[e], sb = csr_src[e + 1];
        uint4 va = h4[(size_t)sa * 16 + lane];
        uint4 vb = h4[(size_t)sb * 16 + lane];
        s0 += bf2f(va.x & 0xffff); s1 += bf2f(va.x >> 16);
        s2 += bf2f(va.y & 0xffff); s3 += bf2f(va.y >> 16);
        s4 += bf2f(va.z & 0xffff); s5 += bf2f(va.z >> 16);
        s6 += bf2f(va.w & 0xffff); s7 += bf2f(va.w >> 16);
        s0 += bf2f(vb.x & 0xffff); s1 += bf2f(vb.x >> 16);
        s2 += bf2f(vb.y & 0xffff); s3 += bf2f(vb.y >> 16);
        s4 += bf2f(vb.z & 0xffff); s5 += bf2f(vb.z >> 16);
        s6 += bf2f(vb.w & 0xffff); s7 += bf2f(vb.w >> 16);
    }
    if (e < e1) {
        uint4 va = h4[(size_t)csr_src[e] * 16 + lane];
        s0 += bf2f(va.x & 0xffff); s1 += bf2f(va.x >> 16);
        s2 += bf2f(va.y & 0xffff); s3 += bf2f(va.y >> 16);
        s4 += bf2f(va.z & 0xffff); s5 += bf2f(va.z >> 16);
        s6 += bf2f(va.w & 0xffff); s7 += bf2f(va.w >> 16);
    }
    uint4 o;
    o.x = f2bf(s0) | ((unsigned)f2bf(s1) << 16);
    o.y = f2bf(s2) | ((unsigned)f2bf(s3) << 16);
    o.z = f2bf(s4) | ((unsigned)f2bf(s5) << 16);
    o.w = f2bf(s6) | ((unsigned)f2bf(s7) << 16);
    ((uint4*)z)[(size_t)node * 16 + lane] = o;
}

// ---------------- fused MLP: h_out = relu(relu(z@W1+b1)@W2+b2 [+xres]) ----------------
// A-fragments for GEMM1 read straight from global z (L2-hot, read once per wave).
// Intermediate t-tile in swizzled LDS; each wave reads back only the rows it
// wrote -> NO barriers. 391 blocks x 4 waves.
template <bool ODD>
__global__ __launch_bounds__(256) void fused_gemm12(const unsigned short* __restrict__ z,
                                                    const unsigned short* __restrict__ Wt1,
                                                    const float* __restrict__ b1,
                                                    const unsigned short* __restrict__ Wt2,
                                                    const float* __restrict__ b2,
                                                    float* __restrict__ xres,
                                                    unsigned short* __restrict__ h_out,
                                                    int N) {
    __shared__ __align__(16) char lds[128 * 256];   // t-tile, bf16, XOR-swizzled
    int t = threadIdx.x;
    int wave = t >> 6, lane = t & 63, l15 = lane & 15, l4 = lane >> 4;
    int wrow = wave * 32;
    int rowbase = blockIdx.x * 128;

    f32x4 acc[2][8];
#pragma unroll
    for (int rt = 0; rt < 2; rt++)
#pragma unroll
        for (int ct = 0; ct < 8; ct++) acc[rt][ct] = (f32x4){0.f, 0.f, 0.f, 0.f};

    // ---- GEMM1: A from global z ----
    int r0 = min(rowbase + wrow + l15, N - 1);
    int r1 = min(rowbase + wrow + 16 + l15, N - 1);
#pragma unroll
    for (int kk = 0; kk < 4; kk++) {
        int k0 = kk * 32 + l4 * 8;
        bf16x8 a0 = *(const bf16x8*)&z[(size_t)r0 * HID + k0];
        bf16x8 a1 = *(const bf16x8*)&z[(size_t)r1 * HID + k0];
#pragma unroll
        for (int ct = 0; ct < 8; ct++) {
            bf16x8 b = *(const bf16x8*)&Wt1[(size_t)(ct * 16 + l15) * HID + k0];
            acc[0][ct] = __builtin_amdgcn_mfma_f32_16x16x32_bf16(a0, b, acc[0][ct], 0, 0, 0);
            acc[1][ct] = __builtin_amdgcn_mfma_f32_16x16x32_bf16(a1, b, acc[1][ct], 0, 0, 0);
        }
    }

    // ---- epilogue1: relu(acc+b1) -> LDS (own wave's rows only) ----
#pragma unroll
    for (int ct = 0; ct < 8; ct++) {
        int col = ct * 16 + l15;
        float bc = b1[col];
#pragma unroll
        for (int rt = 0; rt < 2; rt++)
#pragma unroll
            for (int j = 0; j < 4; j++) {
                int r = wrow + rt * 16 + l4 * 4 + j;
                float v = fmaxf(acc[rt][ct][j] + bc, 0.f);
                *(unsigned short*)(lds + r * 256 + ((col * 2) ^ ((r & 7) << 4))) = f2bf(v);
            }
    }

    // ---- GEMM2: A from LDS (rows this wave wrote; no barrier needed) ----
#pragma unroll
    for (int rt = 0; rt < 2; rt++)
#pragma unroll
        for (int ct = 0; ct < 8; ct++) acc[rt][ct] = (f32x4){0.f, 0.f, 0.f, 0.f};
    int lr0 = wrow + l15, lr1 = lr0 + 16;
#pragma unroll
    for (int kk = 0; kk < 4; kk++) {
        int k0 = kk * 32 + l4 * 8;
        bf16x8 a0 = *(const bf16x8*)(lds + lr0 * 256 + ((k0 * 2) ^ ((lr0 & 7) << 4)));
        bf16x8 a1 = *(const bf16x8*)(lds + lr1 * 256 + ((k0 * 2) ^ ((lr1 & 7) << 4)));
#pragma unroll
        for (int ct = 0; ct < 8; ct++) {
            bf16x8 b = *(const bf16x8*)&Wt2[(size_t)(ct * 16 + l15) * HID + k0];
            acc[0][ct] = __builtin_amdgcn_mfma_f32_16x16x32_bf16(a0, b, acc[0][ct], 0, 0, 0);
            acc[1][ct] = __builtin_amdgcn_mfma_f32_16x16x32_bf16(a1, b, acc[1][ct], 0, 0, 0);
        }
    }

    // ---- epilogue2: +b2 [,+xres], h_out = relu ----
#pragma unroll
    for (int ct = 0; ct < 8; ct++) {
        int col = ct * 16 + l15;
        float bc = b2[col];
#pragma unroll
        for (int rt = 0; rt < 2; rt++)
#pragma unroll
            for (int j = 0; j < 4; j++) {
                int r = wrow + rt * 16 + l4 * 4 + j;
                int rg = rowbase + r;
                if (rg < N) {
                    float v = acc[rt][ct][j] + bc;
                    if (ODD) {
                        v += xres[(size_t)rg * HID + col];
                        xres[(size_t)rg * HID + col] = v;
                    }
                    h_out[(size_t)rg * HID + col] = f2bf(fmaxf(v, 0.f));
                }
            }
    }
}

// ---------------- pre linear (MFMA, global in) ----------------
__global__ __launch_bounds__(256) void linear_pre(const unsigned short* __restrict__ in,
                                                  const unsigned short* __restrict__ Wt,
                                                  const float* __restrict__ bias,
                                                  unsigned short* __restrict__ out,
                                                  float* __restrict__ pre_out, int M) {
    int tid = threadIdx.x;
    int wave = tid >> 6, lane = tid & 63;
    int l15 = lane & 15, l4 = lane >> 4;
    int rowbase = blockIdx.x * 128 + wave * 32;
    f32x4 acc[2][8];
#pragma unroll
    for (int rt = 0; rt < 2; rt++)
#pragma unroll
        for (int ct = 0; ct < 8; ct++) acc[rt][ct] = (f32x4){0.f, 0.f, 0.f, 0.f};
    int r0 = min(rowbase + l15, M - 1);
    int r1 = min(rowbase + 16 + l15, M - 1);
#pragma unroll
    for (int kk = 0; kk < 4; kk++) {
        int k0 = kk * 32 + l4 * 8;
        bf16x8 a0 = *(const bf16x8*)&in[(size_t)r0 * HID + k0];
        bf16x8 a1 = *(const bf16x8*)&in[(size_t)r1 * HID + k0];
#pragma unroll
        for (int ct = 0; ct < 8; ct++) {
            bf16x8 b = *(const bf16x8*)&Wt[(size_t)(ct * 16 + l15) * HID + k0];
            acc[0][ct] = __builtin_amdgcn_mfma_f32_16x16x32_bf16(a0, b, acc[0][ct], 0, 0, 0);
            acc[1][ct] = __builtin_amdgcn_mfma_f32_16x16x32_bf16(a1, b, acc[1][ct], 0, 0, 0);
        }
    }
#pragma unroll
    for (int ct = 0; ct < 8; ct++) {
        int col = ct * 16 + l15;
        float bc = bias[col];
#pragma unroll
        for (int rt = 0; rt < 2; rt++)
#pragma unroll
            for (int j = 0; j < 4; j++) {
                int r = rowbase + rt * 16 + l4 * 4 + j;
                if (r < M) {
                    float v = acc[rt][ct][j] + bc;
                    pre_out[(size_t)r * HID + col] = v;   // xres fp32
                    out[(size_t)r * HID + col] = f2bf(v); // h slice 0 (no relu)
                }
            }
    }
}

// ---------------- pooling: 2-level deterministic ----------------
// level 1: 8 partial blocks per graph, fixed slots
__global__ __launch_bounds__(128) void pool_part(const unsigned short* __restrict__ h,
                                                 const int* __restrict__ gstart,
                                                 float* __restrict__ part,
                                                 int off, int EMB) {
    int g = blockIdx.x >> 3, sub = blockIdx.x & 7;
    int c = threadIdx.x;
    int n0 = gstart[g], n1 = gstart[g + 1];
    float s = 0.f;
    for (int n = n0 + sub; n < n1; n += 8) s += bf2f(h[(size_t)n * HID + c]);
    part[(size_t)blockIdx.x * EMB + off + c] = s;
}

// level 2: sum the 8 partials for every (graph, slice) -> bf16 pooled
__global__ __launch_bounds__(128) void pool_final(const float* __restrict__ part,
                                                  unsigned short* __restrict__ pooled,
                                                  int EMB, int nslice) {
    int g = blockIdx.x / nslice, slice = blockIdx.x % nslice;
    int idx = slice * HID + threadIdx.x;
    float s = 0.f;
#pragma unroll
    for (int sub = 0; sub < 8; sub++)
        s += part[(size_t)(g * 8 + sub) * EMB + idx];
    pooled[(size_t)g * EMB + idx] = f2bf(s);
}

// ---------------- post MLP via MFMA ----------------
__global__ __launch_bounds__(256) void post_mfma(const unsigned short* __restrict__ pooled,
                                                 const unsigned short* __restrict__ w1t,
                                                 const float* __restrict__ b1,
                                                 const unsigned short* __restrict__ w2t,
                                                 const float* __restrict__ b2,
                                                 float* __restrict__ out, int EMB) {
    __shared__ __align__(16) char lds[128 * 256];
    int t = threadIdx.x;
    int wave = t >> 6, lane = t & 63, l15 = lane & 15, l4 = lane >> 4;
    int wrow = wave * 32;
    f32x4 acc[2][8];
#pragma unroll
    for (int rt = 0; rt < 2; rt++)
#pragma unroll
        for (int ct = 0; ct < 8; ct++) acc[rt][ct] = (f32x4){0.f, 0.f, 0.f, 0.f};
    int r0 = wrow + l15, r1 = r0 + 16;
#pragma unroll 4
    for (int kk = 0; kk < EMB / 32; kk++) {
        int k0 = kk * 32 + l4 * 8;
        bf16x8 a0 = *(const bf16x8*)&pooled[(size_t)r0 * EMB + k0];
        bf16x8 a1 = *(const bf16x8*)&pooled[(size_t)r1 * EMB + k0];
#pragma unroll
        for (int ct = 0; ct < 8; ct++) {
            bf16x8 b = *(const bf16x8*)&w1t[(size_t)(ct * 16 + l15) * EMB + k0];
            acc[0][ct] = __builtin_amdgcn_mfma_f32_16x16x32_bf16(a0, b, acc[0][ct], 0, 0, 0);
            acc[1][ct] = __builtin_amdgcn_mfma_f32_16x16x32_bf16(a1, b, acc[1][ct], 0, 0, 0);
        }
    }
#pragma unroll
    for (int ct = 0; ct < 8; ct++) {
        int col = ct * 16 + l15;
        float bc = b1[col];
#pragma unroll
        for (int rt = 0; rt < 2; rt++)
#pragma unroll
            for (int j = 0; j < 4; j++) {
                int r = wrow + rt * 16 + l4 * 4 + j;
                float v = fmaxf(acc[rt][ct][j] + bc, 0.f);
                *(unsigned short*)(lds + r * 256 + ((col * 2) ^ ((r & 7) << 4))) = f2bf(v);
            }
    }
    __syncthreads();
#pragma unroll
    for (int rt = 0; rt < 2; rt++)
#pragma unroll
        for (int ct = 0; ct < 8; ct++) acc[rt][ct] = (f32x4){0.f, 0.f, 0.f, 0.f};
#pragma unroll
    for (int kk = 0; kk < 4; kk++) {
        int k0 = kk * 32 + l4 * 8;
        bf16x8 a0 = *(const bf16x8*)(lds + r0 * 256 + ((k0 * 2) ^ ((r0 & 7) << 4)));
        bf16x8 a1 = *(const bf16x8*)(lds + r1 * 256 + ((k0 * 2) ^ ((r1 & 7) << 4)));
#pragma unroll
        for (int ct = 0; ct < 8; ct++) {
            bf16x8 b = *(const bf16x8*)&w2t[(size_t)(ct * 16 + l15) * HID + k0];
            acc[0][ct] = __builtin_amdgcn_mfma_f32_16x16x32_bf16(a0, b, acc[0][ct], 0, 0, 0);
            acc[1][ct] = __builtin_amdgcn_mfma_f32_16x16x32_bf16(a1, b, acc[1][ct], 0, 0, 0);
        }
    }
#pragma unroll
    for (int ct = 0; ct < 8; ct++) {
        int col = ct * 16 + l15;
        float bc = b2[col];
#pragma unroll
        for (int rt = 0; rt < 2; rt++)
#pragma unroll
            for (int j = 0; j < 4; j++) {
                int r = wrow + rt * 16 + l4 * 4 + j;
                out[(size_t)r * HID + col] = acc[rt][ct][j] + bc;
            }
    }
}

// ---------------- launch ----------------

extern "C" void kernel_launch(void* const* d_in, const int* in_sizes, int n_in,
                              void* d_out, int out_size, void* d_ws, size_t ws_size,
                              hipStream_t stream) {
    const float* x       = (const float*)d_in[0];
    const int* edge_index= (const int*)d_in[1];
    const int* batch     = (const int*)d_in[2];
    const float* pre_w   = (const float*)d_in[3];
    const float* pre_b   = (const float*)d_in[4];
    const float* conv_w1 = (const float*)d_in[5];
    const float* conv_b1 = (const float*)d_in[6];
    const float* conv_w2 = (const float*)d_in[7];
    const float* conv_b2 = (const float*)d_in[8];
    const float* post_w1 = (const float*)d_in[9];
    const float* post_b1 = (const float*)d_in[10];
    const float* post_w2 = (const float*)d_in[11];
    const float* post_b2 = (const float*)d_in[12];
    float* outp = (float*)d_out;

    int N = in_sizes[0] / HID;
    int E = in_sizes[1] / 2;
    int L = in_sizes[5] / (HID * HID);
    int G = out_size / HID;
    int EMB = (L + 1) * HID;

    const int* src = edge_index;
    const int* dst = edge_index + E;

    char* w = (char*)d_ws;
    auto alloc = [&](size_t bytes) -> char* {
        char* p = w;
        w += (bytes + 255) & ~(size_t)255;
        return p;
    };
    unsigned short* x_bf  = (unsigned short*)alloc((size_t)N * HID * 2);
    unsigned short* hA    = (unsigned short*)alloc((size_t)N * HID * 2);
    unsigned short* hB    = (unsigned short*)alloc((size_t)N * HID * 2);
    unsigned short* z_bf  = (unsigned short*)alloc((size_t)N * HID * 2);
    float* xres   = (float*)alloc((size_t)N * HID * 4);
    float* part   = (float*)alloc((size_t)G * 8 * EMB * 4);
    unsigned short* pooled = (unsigned short*)alloc((size_t)G * EMB * 2);
    unsigned short* Wt_pre = (unsigned short*)alloc((size_t)HID * HID * 2);
    unsigned short* Wt_c1  = (unsigned short*)alloc((size_t)L * HID * HID * 2);
    unsigned short* Wt_c2  = (unsigned short*)alloc((size_t)L * HID * HID * 2);
    unsigned short* w1t    = (unsigned short*)alloc((size_t)EMB * HID * 2);
    unsigned short* w2t    = (unsigned short*)alloc((size_t)HID * HID * 2);
    int* deg      = (int*)alloc((size_t)(N + 1) * 4);
    int* row_ptr  = (int*)alloc((size_t)(N + 1) * 4);
    int* pos      = (int*)alloc((size_t)(N + 1) * 4);
    int* bsum     = (int*)alloc((size_t)1024 * 4);
    int* bstart   = (int*)alloc((size_t)1024 * 4);
    int* csr_src  = (int*)alloc((size_t)E * 4);
    int* gstart   = (int*)alloc((size_t)(G + 1) * 4);
    (void)ws_size; (void)n_in;

    int eb = (E + 255) / 256;
    int nb = (N + 255) / 256;

    // CSR by dst
    zero_i32<<<nb, 256, 0, stream>>>(deg, N);
    count_deg<<<eb, 256, 0, stream>>>(dst, deg, E);
    block_sums<<<nb, 256, 0, stream>>>(deg, bsum, N);
    scan_bsums<<<1, 1024, 0, stream>>>(bsum, bstart, nb);
    scan_within<<<nb, 256, 0, stream>>>(deg, bstart, row_ptr, pos, N);
    fill_csr<<<eb, 256, 0, stream>>>(src, dst, pos, csr_src, E);
    graph_starts<<<1, 256, 0, stream>>>(batch, gstart, N, G);

    // conversions / transposes
    f32_to_bf16_vec<<<(N * HID / 8 + 255) / 256, 256, 0, stream>>>(x, x_bf, N * HID / 8);
    transpose_kc<<<(HID * HID + 255) / 256, 256, 0, stream>>>(pre_w, Wt_pre, HID, HID, HID * HID);
    transpose_kc<<<(L * HID * HID + 255) / 256, 256, 0, stream>>>(conv_w1, Wt_c1, HID, HID, L * HID * HID);
    transpose_kc<<<(L * HID * HID + 255) / 256, 256, 0, stream>>>(conv_w2, Wt_c2, HID, HID, L * HID * HID);
    transpose_kc<<<(EMB * HID + 255) / 256, 256, 0, stream>>>(post_w1, w1t, EMB, HID, EMB * HID);
    transpose_kc<<<(HID * HID + 255) / 256, 256, 0, stream>>>(post_w2, w2t, HID, HID, HID * HID);

    int gb = (N + 127) / 128;

    // pre linear: h = x@pre_w + pre_b ; xres = h (fp32)
    linear_pre<<<gb, 256, 0, stream>>>(x_bf, Wt_pre, pre_b, hA, xres, N);
    pool_part<<<G * 8, 128, 0, stream>>>(hA, gstart, part, 0, EMB);

    unsigned short* hcur = hA;
    unsigned short* hnxt = hB;
    for (int i = 0; i < L; i++) {
        agg_kernel<<<(N + 15) / 16, 256, 0, stream>>>(hcur, row_ptr, csr_src, z_bf, N);
        if (i & 1) {
            fused_gemm12<true><<<gb, 256, 0, stream>>>(
                z_bf, Wt_c1 + (size_t)i * HID * HID, conv_b1 + i * HID,
                Wt_c2 + (size_t)i * HID * HID, conv_b2 + i * HID, xres, hnxt, N);
        } else {
            fused_gemm12<false><<<gb, 256, 0, stream>>>(
                z_bf, Wt_c1 + (size_t)i * HID * HID, conv_b1 + i * HID,
                Wt_c2 + (size_t)i * HID * HID, conv_b2 + i * HID, xres, hnxt, N);
        }
        pool_part<<<G * 8, 128, 0, stream>>>(hnxt, gstart, part, (i + 1) * HID, EMB);
        unsigned short* tmp = hcur; hcur = hnxt; hnxt = tmp;
    }

    pool_final<<<G * (L + 1), 128, 0, stream>>>(part, pooled, EMB, L + 1);
    post_mfma<<<1, 256, 0, stream>>>(pooled, w1t, post_b1, w2t, post_b2, outp, EMB);
}

// Round 6
// 653.192 us; speedup vs baseline: 1.3481x; 1.0498x over previous
//
#include <hip/hip_runtime.h>
#include <hip/hip_bf16.h>

#define HID 128

using bf16x8 = __attribute__((ext_vector_type(8))) short;
using f32x4  = __attribute__((ext_vector_type(4))) float;

__device__ inline float bf2f(unsigned int u16) {
    union { float f; unsigned int i; } v; v.i = u16 << 16; return v.f;
}
__device__ inline unsigned short f2bf(float f) {
    __hip_bfloat16 h = __float2bfloat16(f);        // RNE
    return *reinterpret_cast<unsigned short*>(&h);
}

// ---------------- CSR build ----------------

__global__ void zero_i32(int* __restrict__ p, int n) {
    int i = blockIdx.x * blockDim.x + threadIdx.x;
    if (i < n) p[i] = 0;
}

__global__ void count_deg(const int* __restrict__ dst, int* __restrict__ deg, int E) {
    int e = blockIdx.x * blockDim.x + threadIdx.x;
    if (e < E) atomicAdd(&deg[dst[e]], 1);
}

__global__ __launch_bounds__(256) void block_sums(const int* __restrict__ deg,
                                                  int* __restrict__ bsum, int n) {
    __shared__ int red[256];
    int t = threadIdx.x;
    int i = blockIdx.x * 256 + t;
    red[t] = (i < n) ? deg[i] : 0;
    __syncthreads();
    for (int off = 128; off > 0; off >>= 1) {
        if (t < off) red[t] += red[t + off];
        __syncthreads();
    }
    if (t == 0) bsum[blockIdx.x] = red[0];
}

__global__ __launch_bounds__(1024) void scan_bsums(const int* __restrict__ bsum,
                                                   int* __restrict__ bstart, int nb) {
    __shared__ int s[1024];
    int t = threadIdx.x;
    s[t] = (t < nb) ? bsum[t] : 0;
    __syncthreads();
    for (int off = 1; off < 1024; off <<= 1) {
        int v = (t >= off) ? s[t - off] : 0;
        __syncthreads();
        s[t] += v;
        __syncthreads();
    }
    if (t < nb) bstart[t] = (t == 0) ? 0 : s[t - 1];
}

__global__ __launch_bounds__(256) void scan_within(const int* __restrict__ deg,
                                                   const int* __restrict__ bstart,
                                                   int* __restrict__ row_ptr,
                                                   int* __restrict__ pos, int n) {
    __shared__ int s[256];
    int b = blockIdx.x, t = threadIdx.x;
    int i = b * 256 + t;
    int v = (i < n) ? deg[i] : 0;
    s[t] = v;
    __syncthreads();
    for (int off = 1; off < 256; off <<= 1) {
        int u = (t >= off) ? s[t - off] : 0;
        __syncthreads();
        s[t] += u;
        __syncthreads();
    }
    if (i < n) {
        int excl = bstart[b] + s[t] - v;
        row_ptr[i] = excl;
        pos[i] = excl;
        if (i == n - 1) row_ptr[n] = bstart[b] + s[t];
    }
}

__global__ void fill_csr(const int* __restrict__ src, const int* __restrict__ dst,
                         int* __restrict__ pos, int* __restrict__ csr_src, int E) {
    int e = blockIdx.x * blockDim.x + threadIdx.x;
    if (e < E) {
        int p = atomicAdd(&pos[dst[e]], 1);
        csr_src[p] = src[e];
    }
}

__global__ void graph_starts(const int* __restrict__ batch, int* __restrict__ gstart,
                             int n, int G) {
    int g = blockIdx.x * blockDim.x + threadIdx.x;
    if (g > G) return;
    int lo = 0, hi = n;
    while (lo < hi) { int m = (lo + hi) >> 1; if (batch[m] < g) lo = m + 1; else hi = m; }
    gstart[g] = lo;
}

// ---------------- conversions ----------------

__global__ void f32_to_bf16_vec(const float* __restrict__ in,
                                unsigned short* __restrict__ out, int n8) {
    int i = blockIdx.x * blockDim.x + threadIdx.x;
    if (i >= n8) return;
    const float4* in4 = (const float4*)in;
    float4 a = in4[i * 2], b = in4[i * 2 + 1];
    uint4 o;
    o.x = f2bf(a.x) | ((unsigned)f2bf(a.y) << 16);
    o.y = f2bf(a.z) | ((unsigned)f2bf(a.w) << 16);
    o.z = f2bf(b.x) | ((unsigned)f2bf(b.y) << 16);
    o.w = f2bf(b.z) | ((unsigned)f2bf(b.w) << 16);
    ((uint4*)out)[i] = o;
}

// W[mat][k][c] fp32 -> Wt[mat][c][k] bf16
__global__ void transpose_kc(const float* __restrict__ W, unsigned short* __restrict__ Wt,
                             int K, int C, int total) {
    int tid = blockIdx.x * blockDim.x + threadIdx.x;
    if (tid >= total) return;
    int kc = K * C;
    int mat = tid / kc;
    int rem = tid - mat * kc;
    int c = rem / K;
    int k = rem - c * K;
    Wt[tid] = f2bf(W[(size_t)mat * kc + (size_t)k * C + c]);
}

// ---------------- aggregation: z = h + sum_in-edges h[src] ----------------
// h lives in emb[N][EMB] at slice offset; 16 lanes/node (16B), 16 nodes/block.
__global__ __launch_bounds__(256) void agg_kernel(const unsigned short* __restrict__ emb,
                                                  int slice_u4, int row_u4,
                                                  const int* __restrict__ row_ptr,
                                                  const int* __restrict__ csr_src,
                                                  unsigned short* __restrict__ z, int N) {
    int node = blockIdx.x * 16 + (threadIdx.x >> 4);
    int lane = threadIdx.x & 15;
    if (node >= N) return;
    const uint4* h4 = (const uint4*)emb;
    uint4 u = h4[(size_t)node * row_u4 + slice_u4 + lane];
    float s0 = bf2f(u.x & 0xffff), s1 = bf2f(u.x >> 16);
    float s2 = bf2f(u.y & 0xffff), s3 = bf2f(u.y >> 16);
    float s4 = bf2f(u.z & 0xffff), s5 = bf2f(u.z >> 16);
    float s6 = bf2f(u.w & 0xffff), s7 = bf2f(u.w >> 16);
    int e0 = row_ptr[node], e1 = row_ptr[node + 1];
    int e = e0;
    for (; e + 3 < e1; e += 4) {
        int sa = csr_src[e], sb = csr_src[e + 1], sc = csr_src[e + 2], sd = csr_src[e + 3];
        uint4 va = h4[(size_t)sa * row_u4 + slice_u4 + lane];
        uint4 vb = h4[(size_t)sb * row_u4 + slice_u4 + lane];
        uint4 vc = h4[(size_t)sc * row_u4 + slice_u4 + lane];
        uint4 vd = h4[(size_t)sd * row_u4 + slice_u4 + lane];
        s0 += bf2f(va.x & 0xffff); s1 += bf2f(va.x >> 16);
        s2 += bf2f(va.y & 0xffff); s3 += bf2f(va.y >> 16);
        s4 += bf2f(va.z & 0xffff); s5 += bf2f(va.z >> 16);
        s6 += bf2f(va.w & 0xffff); s7 += bf2f(va.w >> 16);
        s0 += bf2f(vb.x & 0xffff); s1 += bf2f(vb.x >> 16);
        s2 += bf2f(vb.y & 0xffff); s3 += bf2f(vb.y >> 16);
        s4 += bf2f(vb.z & 0xffff); s5 += bf2f(vb.z >> 16);
        s6 += bf2f(vb.w & 0xffff); s7 += bf2f(vb.w >> 16);
        s0 += bf2f(vc.x & 0xffff); s1 += bf2f(vc.x >> 16);
        s2 += bf2f(vc.y & 0xffff); s3 += bf2f(vc.y >> 16);
        s4 += bf2f(vc.z & 0xffff); s5 += bf2f(vc.z >> 16);
        s6 += bf2f(vc.w & 0xffff); s7 += bf2f(vc.w >> 16);
        s0 += bf2f(vd.x & 0xffff); s1 += bf2f(vd.x >> 16);
        s2 += bf2f(vd.y & 0xffff); s3 += bf2f(vd.y >> 16);
        s4 += bf2f(vd.z & 0xffff); s5 += bf2f(vd.z >> 16);
        s6 += bf2f(vd.w & 0xffff); s7 += bf2f(vd.w >> 16);
    }
    for (; e < e1; e++) {
        uint4 va = h4[(size_t)csr_src[e] * row_u4 + slice_u4 + lane];
        s0 += bf2f(va.x & 0xffff); s1 += bf2f(va.x >> 16);
        s2 += bf2f(va.y & 0xffff); s3 += bf2f(va.y >> 16);
        s4 += bf2f(va.z & 0xffff); s5 += bf2f(va.z >> 16);
        s6 += bf2f(va.w & 0xffff); s7 += bf2f(va.w >> 16);
    }
    uint4 o;
    o.x = f2bf(s0) | ((unsigned)f2bf(s1) << 16);
    o.y = f2bf(s2) | ((unsigned)f2bf(s3) << 16);
    o.z = f2bf(s4) | ((unsigned)f2bf(s5) << 16);
    o.w = f2bf(s6) | ((unsigned)f2bf(s7) << 16);
    ((uint4*)z)[(size_t)node * 16 + lane] = o;
}

// ---------------- fused MLP: emb_slice = relu(relu(z@W1+b1)@W2+b2 [+xres]) ----------------
// 64-row blocks (782 -> ~3 blocks/CU), 4 waves x 16 rows. t-tile in swizzled
// LDS; each wave reads back only its own rows -> no barriers.
template <bool ODD>
__global__ __launch_bounds__(256) void fused_gemm12(const unsigned short* __restrict__ z,
                                                    const unsigned short* __restrict__ Wt1,
                                                    const float* __restrict__ b1,
                                                    const unsigned short* __restrict__ Wt2,
                                                    const float* __restrict__ b2,
                                                    float* __restrict__ xres,
                                                    unsigned short* __restrict__ h_out,
                                                    int out_stride, int N) {
    __shared__ __align__(16) char lds[64 * 256];   // bf16 t-tile, XOR-swizzled
    int t = threadIdx.x;
    int wave = t >> 6, lane = t & 63, l15 = lane & 15, l4 = lane >> 4;
    int wrow = wave * 16;
    int rowbase = blockIdx.x * 64;

    f32x4 acc[8];
#pragma unroll
    for (int ct = 0; ct < 8; ct++) acc[ct] = (f32x4){0.f, 0.f, 0.f, 0.f};

    // ---- GEMM1: A from global z ----
    int r0 = min(rowbase + wrow + l15, N - 1);
#pragma unroll
    for (int kk = 0; kk < 4; kk++) {
        int k0 = kk * 32 + l4 * 8;
        bf16x8 a0 = *(const bf16x8*)&z[(size_t)r0 * HID + k0];
#pragma unroll
        for (int ct = 0; ct < 8; ct++) {
            bf16x8 b = *(const bf16x8*)&Wt1[(size_t)(ct * 16 + l15) * HID + k0];
            acc[ct] = __builtin_amdgcn_mfma_f32_16x16x32_bf16(a0, b, acc[ct], 0, 0, 0);
        }
    }

    // ---- epilogue1: relu(acc+b1) -> LDS (own wave's rows) ----
#pragma unroll
    for (int ct = 0; ct < 8; ct++) {
        int col = ct * 16 + l15;
        float bc = b1[col];
#pragma unroll
        for (int j = 0; j < 4; j++) {
            int r = wrow + l4 * 4 + j;
            float v = fmaxf(acc[ct][j] + bc, 0.f);
            *(unsigned short*)(lds + r * 256 + ((col * 2) ^ ((r & 7) << 4))) = f2bf(v);
        }
    }

    // ---- GEMM2: A from LDS (no barrier; same wave's rows) ----
#pragma unroll
    for (int ct = 0; ct < 8; ct++) acc[ct] = (f32x4){0.f, 0.f, 0.f, 0.f};
    int lr0 = wrow + l15;
#pragma unroll
    for (int kk = 0; kk < 4; kk++) {
        int k0 = kk * 32 + l4 * 8;
        bf16x8 a0 = *(const bf16x8*)(lds + lr0 * 256 + ((k0 * 2) ^ ((lr0 & 7) << 4)));
#pragma unroll
        for (int ct = 0; ct < 8; ct++) {
            bf16x8 b = *(const bf16x8*)&Wt2[(size_t)(ct * 16 + l15) * HID + k0];
            acc[ct] = __builtin_amdgcn_mfma_f32_16x16x32_bf16(a0, b, acc[ct], 0, 0, 0);
        }
    }

    // ---- epilogue2: +b2 [,+xres], emb slice = relu ----
#pragma unroll
    for (int ct = 0; ct < 8; ct++) {
        int col = ct * 16 + l15;
        float bc = b2[col];
#pragma unroll
        for (int j = 0; j < 4; j++) {
            int r = wrow + l4 * 4 + j;
            int rg = rowbase + r;
            if (rg < N) {
                float v = acc[ct][j] + bc;
                if (ODD) {
                    v += xres[(size_t)rg * HID + col];
                    xres[(size_t)rg * HID + col] = v;
                }
                h_out[(size_t)rg * out_stride + col] = f2bf(fmaxf(v, 0.f));
            }
        }
    }
}

// ---------------- pre linear (MFMA, global in, writes emb slice 0 + xres) ----------------
__global__ __launch_bounds__(256) void linear_pre(const unsigned short* __restrict__ in,
                                                  const unsigned short* __restrict__ Wt,
                                                  const float* __restrict__ bias,
                                                  unsigned short* __restrict__ out,
                                                  int out_stride,
                                                  float* __restrict__ pre_out, int M) {
    int tid = threadIdx.x;
    int wave = tid >> 6, lane = tid & 63;
    int l15 = lane & 15, l4 = lane >> 4;
    int rowbase = blockIdx.x * 64 + wave * 16;
    f32x4 acc[8];
#pragma unroll
    for (int ct = 0; ct < 8; ct++) acc[ct] = (f32x4){0.f, 0.f, 0.f, 0.f};
    int r0 = min(rowbase + l15, M - 1);
#pragma unroll
    for (int kk = 0; kk < 4; kk++) {
        int k0 = kk * 32 + l4 * 8;
        bf16x8 a0 = *(const bf16x8*)&in[(size_t)r0 * HID + k0];
#pragma unroll
        for (int ct = 0; ct < 8; ct++) {
            bf16x8 b = *(const bf16x8*)&Wt[(size_t)(ct * 16 + l15) * HID + k0];
            acc[ct] = __builtin_amdgcn_mfma_f32_16x16x32_bf16(a0, b, acc[ct], 0, 0, 0);
        }
    }
#pragma unroll
    for (int ct = 0; ct < 8; ct++) {
        int col = ct * 16 + l15;
        float bc = bias[col];
#pragma unroll
        for (int j = 0; j < 4; j++) {
            int r = rowbase + l4 * 4 + j;
            if (r < M) {
                float v = acc[ct][j] + bc;
                pre_out[(size_t)r * HID + col] = v;        // xres fp32
                out[(size_t)r * out_stride + col] = f2bf(v); // emb slice 0 (no relu)
            }
        }
    }
}

// ---------------- pooling over full emb, 2-level deterministic ----------------
// level 1: (g, sub) blocks; thread t<112 sums cols 8t..8t+7 over rows n0+sub::8
__global__ __launch_bounds__(128) void pool_all(const unsigned short* __restrict__ emb,
                                                const int* __restrict__ gstart,
                                                float* __restrict__ part, int EMB) {
    int g = blockIdx.x >> 3, sub = blockIdx.x & 7;
    int t = threadIdx.x;
    if (t >= 112) return;
    const uint4* e4 = (const uint4*)emb;     // row stride EMB/8 = 112 uint4
    int row_u4 = EMB / 8;
    int n0 = gstart[g], n1 = gstart[g + 1];
    float s[8] = {0.f, 0.f, 0.f, 0.f, 0.f, 0.f, 0.f, 0.f};
    for (int n = n0 + sub; n < n1; n += 8) {
        uint4 v = e4[(size_t)n * row_u4 + t];
        s[0] += bf2f(v.x & 0xffff); s[1] += bf2f(v.x >> 16);
        s[2] += bf2f(v.y & 0xffff); s[3] += bf2f(v.y >> 16);
        s[4] += bf2f(v.z & 0xffff); s[5] += bf2f(v.z >> 16);
        s[6] += bf2f(v.w & 0xffff); s[7] += bf2f(v.w >> 16);
    }
    float4* p4 = (float4*)&part[(size_t)blockIdx.x * EMB + t * 8];
    p4[0] = (float4){s[0], s[1], s[2], s[3]};
    p4[1] = (float4){s[4], s[5], s[6], s[7]};
}

// level 2: pooled[g][c] = sum of 8 partials, -> bf16
__global__ __launch_bounds__(128) void pool_fin(const float* __restrict__ part,
                                                unsigned short* __restrict__ pooled,
                                                int EMB) {
    int idx = blockIdx.x * 128 + threadIdx.x;   // over G*EMB
    int g = idx / EMB, c = idx - g * EMB;
    float s = 0.f;
#pragma unroll
    for (int sub = 0; sub < 8; sub++)
        s += part[(size_t)(g * 8 + sub) * EMB + c];
    pooled[idx] = f2bf(s);
}

// ---------------- post MLP via MFMA ----------------
__global__ __launch_bounds__(256) void post_mfma(const unsigned short* __restrict__ pooled,
                                                 const unsigned short* __restrict__ w1t,
                                                 const float* __restrict__ b1,
                                                 const unsigned short* __restrict__ w2t,
                                                 const float* __restrict__ b2,
                                                 float* __restrict__ out, int EMB) {
    __shared__ __align__(16) char lds[128 * 256];
    int t = threadIdx.x;
    int wave = t >> 6, lane = t & 63, l15 = lane & 15, l4 = lane >> 4;
    int wrow = wave * 32;
    f32x4 acc[2][8];
#pragma unroll
    for (int rt = 0; rt < 2; rt++)
#pragma unroll
        for (int ct = 0; ct < 8; ct++) acc[rt][ct] = (f32x4){0.f, 0.f, 0.f, 0.f};
    int r0 = wrow + l15, r1 = r0 + 16;
#pragma unroll 4
    for (int kk = 0; kk < EMB / 32; kk++) {
        int k0 = kk * 32 + l4 * 8;
        bf16x8 a0 = *(const bf16x8*)&pooled[(size_t)r0 * EMB + k0];
        bf16x8 a1 = *(const bf16x8*)&pooled[(size_t)r1 * EMB + k0];
#pragma unroll
        for (int ct = 0; ct < 8; ct++) {
            bf16x8 b = *(const bf16x8*)&w1t[(size_t)(ct * 16 + l15) * EMB + k0];
            acc[0][ct] = __builtin_amdgcn_mfma_f32_16x16x32_bf16(a0, b, acc[0][ct], 0, 0, 0);
            acc[1][ct] = __builtin_amdgcn_mfma_f32_16x16x32_bf16(a1, b, acc[1][ct], 0, 0, 0);
        }
    }
#pragma unroll
    for (int ct = 0; ct < 8; ct++) {
        int col = ct * 16 + l15;
        float bc = b1[col];
#pragma unroll
        for (int rt = 0; rt < 2; rt++)
#pragma unroll
            for (int j = 0; j < 4; j++) {
                int r = wrow + rt * 16 + l4 * 4 + j;
                float v = fmaxf(acc[rt][ct][j] + bc, 0.f);
                *(unsigned short*)(lds + r * 256 + ((col * 2) ^ ((r & 7) << 4))) = f2bf(v);
            }
    }
    __syncthreads();
#pragma unroll
    for (int rt = 0; rt < 2; rt++)
#pragma unroll
        for (int ct = 0; ct < 8; ct++) acc[rt][ct] = (f32x4){0.f, 0.f, 0.f, 0.f};
#pragma unroll
    for (int kk = 0; kk < 4; kk++) {
        int k0 = kk * 32 + l4 * 8;
        bf16x8 a0 = *(const bf16x8*)(lds + r0 * 256 + ((k0 * 2) ^ ((r0 & 7) << 4)));
        bf16x8 a1 = *(const bf16x8*)(lds + r1 * 256 + ((k0 * 2) ^ ((r1 & 7) << 4)));
#pragma unroll
        for (int ct = 0; ct < 8; ct++) {
            bf16x8 b = *(const bf16x8*)&w2t[(size_t)(ct * 16 + l15) * HID + k0];
            acc[0][ct] = __builtin_amdgcn_mfma_f32_16x16x32_bf16(a0, b, acc[0][ct], 0, 0, 0);
            acc[1][ct] = __builtin_amdgcn_mfma_f32_16x16x32_bf16(a1, b, acc[1][ct], 0, 0, 0);
        }
    }
#pragma unroll
    for (int ct = 0; ct < 8; ct++) {
        int col = ct * 16 + l15;
        float bc = b2[col];
#pragma unroll
        for (int rt = 0; rt < 2; rt++)
#pragma unroll
            for (int j = 0; j < 4; j++) {
                int r = wrow + rt * 16 + l4 * 4 + j;
                out[(size_t)r * HID + col] = acc[rt][ct][j] + bc;
            }
    }
}

// ---------------- launch ----------------

extern "C" void kernel_launch(void* const* d_in, const int* in_sizes, int n_in,
                              void* d_out, int out_size, void* d_ws, size_t ws_size,
                              hipStream_t stream) {
    const float* x       = (const float*)d_in[0];
    const int* edge_index= (const int*)d_in[1];
    const int* batch     = (const int*)d_in[2];
    const float* pre_w   = (const float*)d_in[3];
    const float* pre_b   = (const float*)d_in[4];
    const float* conv_w1 = (const float*)d_in[5];
    const float* conv_b1 = (const float*)d_in[6];
    const float* conv_w2 = (const float*)d_in[7];
    const float* conv_b2 = (const float*)d_in[8];
    const float* post_w1 = (const float*)d_in[9];
    const float* post_b1 = (const float*)d_in[10];
    const float* post_w2 = (const float*)d_in[11];
    const float* post_b2 = (const float*)d_in[12];
    float* outp = (float*)d_out;

    int N = in_sizes[0] / HID;
    int E = in_sizes[1] / 2;
    int L = in_sizes[5] / (HID * HID);
    int G = out_size / HID;
    int EMB = (L + 1) * HID;

    const int* src = edge_index;
    const int* dst = edge_index + E;

    char* w = (char*)d_ws;
    auto alloc = [&](size_t bytes) -> char* {
        char* p = w;
        w += (bytes + 255) & ~(size_t)255;
        return p;
    };
    unsigned short* emb   = (unsigned short*)alloc((size_t)N * EMB * 2);     // all layer embeddings
    unsigned short* z_bf  = (unsigned short*)alloc((size_t)N * HID * 2);     // also used as x_bf
    float* xres   = (float*)alloc((size_t)N * HID * 4);
    float* part   = (float*)alloc((size_t)G * 8 * EMB * 4);
    unsigned short* pooled = (unsigned short*)alloc((size_t)G * EMB * 2);
    unsigned short* Wt_pre = (unsigned short*)alloc((size_t)HID * HID * 2);
    unsigned short* Wt_c1  = (unsigned short*)alloc((size_t)L * HID * HID * 2);
    unsigned short* Wt_c2  = (unsigned short*)alloc((size_t)L * HID * HID * 2);
    unsigned short* w1t    = (unsigned short*)alloc((size_t)EMB * HID * 2);
    unsigned short* w2t    = (unsigned short*)alloc((size_t)HID * HID * 2);
    int* deg      = (int*)alloc((size_t)(N + 1) * 4);
    int* row_ptr  = (int*)alloc((size_t)(N + 1) * 4);
    int* pos      = (int*)alloc((size_t)(N + 1) * 4);
    int* bsum     = (int*)alloc((size_t)1024 * 4);
    int* bstart   = (int*)alloc((size_t)1024 * 4);
    int* csr_src  = (int*)alloc((size_t)E * 4);
    int* gstart   = (int*)alloc((size_t)(G + 1) * 4);
    (void)ws_size; (void)n_in;

    int eb = (E + 255) / 256;
    int nb = (N + 255) / 256;

    // CSR by dst
    zero_i32<<<nb, 256, 0, stream>>>(deg, N);
    count_deg<<<eb, 256, 0, stream>>>(dst, deg, E);
    block_sums<<<nb, 256, 0, stream>>>(deg, bsum, N);
    scan_bsums<<<1, 1024, 0, stream>>>(bsum, bstart, nb);
    scan_within<<<nb, 256, 0, stream>>>(deg, bstart, row_ptr, pos, N);
    fill_csr<<<eb, 256, 0, stream>>>(src, dst, pos, csr_src, E);
    graph_starts<<<1, 256, 0, stream>>>(batch, gstart, N, G);

    // conversions / transposes (x_bf aliases z_bf; consumed by linear_pre before agg runs)
    f32_to_bf16_vec<<<(N * HID / 8 + 255) / 256, 256, 0, stream>>>(x, z_bf, N * HID / 8);
    transpose_kc<<<(HID * HID + 255) / 256, 256, 0, stream>>>(pre_w, Wt_pre, HID, HID, HID * HID);
    transpose_kc<<<(L * HID * HID + 255) / 256, 256, 0, stream>>>(conv_w1, Wt_c1, HID, HID, L * HID * HID);
    transpose_kc<<<(L * HID * HID + 255) / 256, 256, 0, stream>>>(conv_w2, Wt_c2, HID, HID, L * HID * HID);
    transpose_kc<<<(EMB * HID + 255) / 256, 256, 0, stream>>>(post_w1, w1t, EMB, HID, EMB * HID);
    transpose_kc<<<(HID * HID + 255) / 256, 256, 0, stream>>>(post_w2, w2t, HID, HID, HID * HID);

    int gb64 = (N + 63) / 64;

    // pre linear: emb slice0 = x@pre_w + pre_b (no relu) ; xres = same (fp32)
    linear_pre<<<gb64, 256, 0, stream>>>(z_bf, Wt_pre, pre_b, emb, EMB, xres, N);

    for (int i = 0; i < L; i++) {
        agg_kernel<<<(N + 15) / 16, 256, 0, stream>>>(emb, i * 16, EMB / 8, row_ptr, csr_src, z_bf, N);
        unsigned short* slice_out = emb + (size_t)(i + 1) * HID;
        if (i & 1) {
            fused_gemm12<true><<<gb64, 256, 0, stream>>>(
                z_bf, Wt_c1 + (size_t)i * HID * HID, conv_b1 + i * HID,
                Wt_c2 + (size_t)i * HID * HID, conv_b2 + i * HID, xres, slice_out, EMB, N);
        } else {
            fused_gemm12<false><<<gb64, 256, 0, stream>>>(
                z_bf, Wt_c1 + (size_t)i * HID * HID, conv_b1 + i * HID,
                Wt_c2 + (size_t)i * HID * HID, conv_b2 + i * HID, xres, slice_out, EMB, N);
        }
    }

    pool_all<<<G * 8, 128, 0, stream>>>(emb, gstart, part, EMB);
    pool_fin<<<(G * EMB) / 128, 128, 0, stream>>>(part, pooled, EMB);
    post_mfma<<<1, 256, 0, stream>>>(pooled, w1t, post_b1, w2t, post_b2, outp, EMB);
}

// Round 7
// 586.408 us; speedup vs baseline: 1.5016x; 1.1139x over previous
//
#include <hip/hip_runtime.h>
#include <hip/hip_bf16.h>

#define HID 128

using bf16x8 = __attribute__((ext_vector_type(8))) short;
using f32x4  = __attribute__((ext_vector_type(4))) float;

__device__ inline float bf2f(unsigned int u16) {
    union { float f; unsigned int i; } v; v.i = u16 << 16; return v.f;
}
__device__ inline unsigned short f2bf(float f) {
    __hip_bfloat16 h = __float2bfloat16(f);        // RNE
    return *reinterpret_cast<unsigned short*>(&h);
}

// ---------------- CSR build ----------------

__global__ void zero_i32(int* __restrict__ p, int n) {
    int i = blockIdx.x * blockDim.x + threadIdx.x;
    if (i < n) p[i] = 0;
}

__global__ void count_deg(const int* __restrict__ dst, int* __restrict__ deg, int E) {
    int e = blockIdx.x * blockDim.x + threadIdx.x;
    if (e < E) atomicAdd(&deg[dst[e]], 1);
}

__global__ __launch_bounds__(256) void block_sums(const int* __restrict__ deg,
                                                  int* __restrict__ bsum, int n) {
    __shared__ int red[256];
    int t = threadIdx.x;
    int i = blockIdx.x * 256 + t;
    red[t] = (i < n) ? deg[i] : 0;
    __syncthreads();
    for (int off = 128; off > 0; off >>= 1) {
        if (t < off) red[t] += red[t + off];
        __syncthreads();
    }
    if (t == 0) bsum[blockIdx.x] = red[0];
}

__global__ __launch_bounds__(1024) void scan_bsums(const int* __restrict__ bsum,
                                                   int* __restrict__ bstart, int nb) {
    __shared__ int s[1024];
    int t = threadIdx.x;
    s[t] = (t < nb) ? bsum[t] : 0;
    __syncthreads();
    for (int off = 1; off < 1024; off <<= 1) {
        int v = (t >= off) ? s[t - off] : 0;
        __syncthreads();
        s[t] += v;
        __syncthreads();
    }
    if (t < nb) bstart[t] = (t == 0) ? 0 : s[t - 1];
}

__global__ __launch_bounds__(256) void scan_within(const int* __restrict__ deg,
                                                   const int* __restrict__ bstart,
                                                   int* __restrict__ row_ptr,
                                                   int* __restrict__ pos, int n) {
    __shared__ int s[256];
    int b = blockIdx.x, t = threadIdx.x;
    int i = b * 256 + t;
    int v = (i < n) ? deg[i] : 0;
    s[t] = v;
    __syncthreads();
    for (int off = 1; off < 256; off <<= 1) {
        int u = (t >= off) ? s[t - off] : 0;
        __syncthreads();
        s[t] += u;
        __syncthreads();
    }
    if (i < n) {
        int excl = bstart[b] + s[t] - v;
        row_ptr[i] = excl;
        pos[i] = excl;
        if (i == n - 1) row_ptr[n] = bstart[b] + s[t];
    }
}

__global__ void fill_csr(const int* __restrict__ src, const int* __restrict__ dst,
                         int* __restrict__ pos, int* __restrict__ csr_src, int E) {
    int e = blockIdx.x * blockDim.x + threadIdx.x;
    if (e < E) {
        int p = atomicAdd(&pos[dst[e]], 1);
        csr_src[p] = src[e];
    }
}

__global__ void graph_starts(const int* __restrict__ batch, int* __restrict__ gstart,
                             int n, int G) {
    int g = blockIdx.x * blockDim.x + threadIdx.x;
    if (g > G) return;
    int lo = 0, hi = n;
    while (lo < hi) { int m = (lo + hi) >> 1; if (batch[m] < g) lo = m + 1; else hi = m; }
    gstart[g] = lo;
}

// ---------------- conversions ----------------

__global__ void f32_to_bf16_vec(const float* __restrict__ in,
                                unsigned short* __restrict__ out, int n8) {
    int i = blockIdx.x * blockDim.x + threadIdx.x;
    if (i >= n8) return;
    const float4* in4 = (const float4*)in;
    float4 a = in4[i * 2], b = in4[i * 2 + 1];
    uint4 o;
    o.x = f2bf(a.x) | ((unsigned)f2bf(a.y) << 16);
    o.y = f2bf(a.z) | ((unsigned)f2bf(a.w) << 16);
    o.z = f2bf(b.x) | ((unsigned)f2bf(b.y) << 16);
    o.w = f2bf(b.z) | ((unsigned)f2bf(b.w) << 16);
    ((uint4*)out)[i] = o;
}

// W[mat][k][c] fp32 -> Wt[mat][c][k] bf16
__global__ void transpose_kc(const float* __restrict__ W, unsigned short* __restrict__ Wt,
                             int K, int C, int total) {
    int tid = blockIdx.x * blockDim.x + threadIdx.x;
    if (tid >= total) return;
    int kc = K * C;
    int mat = tid / kc;
    int rem = tid - mat * kc;
    int c = rem / K;
    int k = rem - c * K;
    Wt[tid] = f2bf(W[(size_t)mat * kc + (size_t)k * C + c]);
}

// ---------------- aggregation: z = h + sum_in-edges h[src] ----------------
// h lives in emb[N][EMB] at slice offset; 16 lanes/node (16B), 16 nodes/block.
__global__ __launch_bounds__(256) void agg_kernel(const unsigned short* __restrict__ emb,
                                                  int slice_u4, int row_u4,
                                                  const int* __restrict__ row_ptr,
                                                  const int* __restrict__ csr_src,
                                                  unsigned short* __restrict__ z, int N) {
    int node = blockIdx.x * 16 + (threadIdx.x >> 4);
    int lane = threadIdx.x & 15;
    if (node >= N) return;
    const uint4* h4 = (const uint4*)emb;
    uint4 u = h4[(size_t)node * row_u4 + slice_u4 + lane];
    float s0 = bf2f(u.x & 0xffff), s1 = bf2f(u.x >> 16);
    float s2 = bf2f(u.y & 0xffff), s3 = bf2f(u.y >> 16);
    float s4 = bf2f(u.z & 0xffff), s5 = bf2f(u.z >> 16);
    float s6 = bf2f(u.w & 0xffff), s7 = bf2f(u.w >> 16);
    int e0 = row_ptr[node], e1 = row_ptr[node + 1];
    int e = e0;
    for (; e + 3 < e1; e += 4) {
        int sa = csr_src[e], sb = csr_src[e + 1], sc = csr_src[e + 2], sd = csr_src[e + 3];
        uint4 va = h4[(size_t)sa * row_u4 + slice_u4 + lane];
        uint4 vb = h4[(size_t)sb * row_u4 + slice_u4 + lane];
        uint4 vc = h4[(size_t)sc * row_u4 + slice_u4 + lane];
        uint4 vd = h4[(size_t)sd * row_u4 + slice_u4 + lane];
        s0 += bf2f(va.x & 0xffff); s1 += bf2f(va.x >> 16);
        s2 += bf2f(va.y & 0xffff); s3 += bf2f(va.y >> 16);
        s4 += bf2f(va.z & 0xffff); s5 += bf2f(va.z >> 16);
        s6 += bf2f(va.w & 0xffff); s7 += bf2f(va.w >> 16);
        s0 += bf2f(vb.x & 0xffff); s1 += bf2f(vb.x >> 16);
        s2 += bf2f(vb.y & 0xffff); s3 += bf2f(vb.y >> 16);
        s4 += bf2f(vb.z & 0xffff); s5 += bf2f(vb.z >> 16);
        s6 += bf2f(vb.w & 0xffff); s7 += bf2f(vb.w >> 16);
        s0 += bf2f(vc.x & 0xffff); s1 += bf2f(vc.x >> 16);
        s2 += bf2f(vc.y & 0xffff); s3 += bf2f(vc.y >> 16);
        s4 += bf2f(vc.z & 0xffff); s5 += bf2f(vc.z >> 16);
        s6 += bf2f(vc.w & 0xffff); s7 += bf2f(vc.w >> 16);
        s0 += bf2f(vd.x & 0xffff); s1 += bf2f(vd.x >> 16);
        s2 += bf2f(vd.y & 0xffff); s3 += bf2f(vd.y >> 16);
        s4 += bf2f(vd.z & 0xffff); s5 += bf2f(vd.z >> 16);
        s6 += bf2f(vd.w & 0xffff); s7 += bf2f(vd.w >> 16);
    }
    for (; e < e1; e++) {
        uint4 va = h4[(size_t)csr_src[e] * row_u4 + slice_u4 + lane];
        s0 += bf2f(va.x & 0xffff); s1 += bf2f(va.x >> 16);
        s2 += bf2f(va.y & 0xffff); s3 += bf2f(va.y >> 16);
        s4 += bf2f(va.z & 0xffff); s5 += bf2f(va.z >> 16);
        s6 += bf2f(va.w & 0xffff); s7 += bf2f(va.w >> 16);
    }
    uint4 o;
    o.x = f2bf(s0) | ((unsigned)f2bf(s1) << 16);
    o.y = f2bf(s2) | ((unsigned)f2bf(s3) << 16);
    o.z = f2bf(s4) | ((unsigned)f2bf(s5) << 16);
    o.w = f2bf(s6) | ((unsigned)f2bf(s7) << 16);
    ((uint4*)z)[(size_t)node * 16 + lane] = o;
}

// ---------------- fused MLP, col-split: emb_slice = relu(relu(z@W1+b1)@W2+b2 [+xres]) ----------------
// block = 128 thr = 2 waves sharing 16 rows; wave w computes cols [w*64, w*64+64).
// grid = N/16 = 3125 -> ~24 waves/CU. t-tile 4 KB swizzled LDS, one 2-wave barrier.
template <bool ODD>
__global__ __launch_bounds__(128) void fused_gemm12(const unsigned short* __restrict__ z,
                                                    const unsigned short* __restrict__ Wt1,
                                                    const float* __restrict__ b1,
                                                    const unsigned short* __restrict__ Wt2,
                                                    const float* __restrict__ b2,
                                                    unsigned short* __restrict__ xres,
                                                    unsigned short* __restrict__ h_out,
                                                    int out_stride, int N) {
    __shared__ __align__(16) char lds[16 * 256];   // bf16 t-tile [16][128], XOR-swizzled
    int t = threadIdx.x;
    int wave = t >> 6, lane = t & 63, l15 = lane & 15, l4 = lane >> 4;
    int rowbase = blockIdx.x * 16;
    int colbase = wave * 64;

    f32x4 acc[4];
#pragma unroll
    for (int ct = 0; ct < 4; ct++) acc[ct] = (f32x4){0.f, 0.f, 0.f, 0.f};

    // ---- GEMM1: A from global z (L2-hot), 4 col-tiles ----
    int r0 = min(rowbase + l15, N - 1);
#pragma unroll
    for (int kk = 0; kk < 4; kk++) {
        int k0 = kk * 32 + l4 * 8;
        bf16x8 a0 = *(const bf16x8*)&z[(size_t)r0 * HID + k0];
#pragma unroll
        for (int ct = 0; ct < 4; ct++) {
            bf16x8 b = *(const bf16x8*)&Wt1[(size_t)(colbase + ct * 16 + l15) * HID + k0];
            acc[ct] = __builtin_amdgcn_mfma_f32_16x16x32_bf16(a0, b, acc[ct], 0, 0, 0);
        }
    }

    // ---- epilogue1: relu(acc+b1) -> LDS (this wave's 64 cols) ----
#pragma unroll
    for (int ct = 0; ct < 4; ct++) {
        int col = colbase + ct * 16 + l15;
        float bc = b1[col];
#pragma unroll
        for (int j = 0; j < 4; j++) {
            int r = l4 * 4 + j;                     // rows 0..15
            float v = fmaxf(acc[ct][j] + bc, 0.f);
            *(unsigned short*)(lds + r * 256 + ((col * 2) ^ ((r & 7) << 4))) = f2bf(v);
        }
    }
    __syncthreads();

    // ---- GEMM2: A from full t-tile (K=128), output this wave's 64 cols ----
#pragma unroll
    for (int ct = 0; ct < 4; ct++) acc[ct] = (f32x4){0.f, 0.f, 0.f, 0.f};
#pragma unroll
    for (int kk = 0; kk < 4; kk++) {
        int k0 = kk * 32 + l4 * 8;
        bf16x8 a0 = *(const bf16x8*)(lds + l15 * 256 + ((k0 * 2) ^ ((l15 & 7) << 4)));
#pragma unroll
        for (int ct = 0; ct < 4; ct++) {
            bf16x8 b = *(const bf16x8*)&Wt2[(size_t)(colbase + ct * 16 + l15) * HID + k0];
            acc[ct] = __builtin_amdgcn_mfma_f32_16x16x32_bf16(a0, b, acc[ct], 0, 0, 0);
        }
    }

    // ---- epilogue2: +b2 [,+xres bf16], emb slice = relu ----
#pragma unroll
    for (int ct = 0; ct < 4; ct++) {
        int col = colbase + ct * 16 + l15;
        float bc = b2[col];
#pragma unroll
        for (int j = 0; j < 4; j++) {
            int r = l4 * 4 + j;
            int rg = rowbase + r;
            if (rg < N) {
                float v = acc[ct][j] + bc;
                if (ODD) {
                    v += bf2f(xres[(size_t)rg * HID + col]);
                    xres[(size_t)rg * HID + col] = f2bf(v);
                }
                h_out[(size_t)rg * out_stride + col] = f2bf(fmaxf(v, 0.f));
            }
        }
    }
}

// ---------------- pre linear (MFMA, global in, writes emb slice 0 + xres bf16) ----------------
__global__ __launch_bounds__(256) void linear_pre(const unsigned short* __restrict__ in,
                                                  const unsigned short* __restrict__ Wt,
                                                  const float* __restrict__ bias,
                                                  unsigned short* __restrict__ out,
                                                  int out_stride,
                                                  unsigned short* __restrict__ pre_out, int M) {
    int tid = threadIdx.x;
    int wave = tid >> 6, lane = tid & 63;
    int l15 = lane & 15, l4 = lane >> 4;
    int rowbase = blockIdx.x * 64 + wave * 16;
    f32x4 acc[8];
#pragma unroll
    for (int ct = 0; ct < 8; ct++) acc[ct] = (f32x4){0.f, 0.f, 0.f, 0.f};
    int r0 = min(rowbase + l15, M - 1);
#pragma unroll
    for (int kk = 0; kk < 4; kk++) {
        int k0 = kk * 32 + l4 * 8;
        bf16x8 a0 = *(const bf16x8*)&in[(size_t)r0 * HID + k0];
#pragma unroll
        for (int ct = 0; ct < 8; ct++) {
            bf16x8 b = *(const bf16x8*)&Wt[(size_t)(ct * 16 + l15) * HID + k0];
            acc[ct] = __builtin_amdgcn_mfma_f32_16x16x32_bf16(a0, b, acc[ct], 0, 0, 0);
        }
    }
#pragma unroll
    for (int ct = 0; ct < 8; ct++) {
        int col = ct * 16 + l15;
        float bc = bias[col];
#pragma unroll
        for (int j = 0; j < 4; j++) {
            int r = rowbase + l4 * 4 + j;
            if (r < M) {
                float v = acc[ct][j] + bc;
                unsigned short bv = f2bf(v);
                pre_out[(size_t)r * HID + col] = bv;          // xres bf16
                out[(size_t)r * out_stride + col] = bv;       // emb slice 0 (no relu)
            }
        }
    }
}

// ---------------- pooling over full emb, 2-level deterministic ----------------
__global__ __launch_bounds__(128) void pool_all(const unsigned short* __restrict__ emb,
                                                const int* __restrict__ gstart,
                                                float* __restrict__ part, int EMB) {
    int g = blockIdx.x >> 3, sub = blockIdx.x & 7;
    int t = threadIdx.x;
    if (t >= 112) return;
    const uint4* e4 = (const uint4*)emb;     // row stride EMB/8 = 112 uint4
    int row_u4 = EMB / 8;
    int n0 = gstart[g], n1 = gstart[g + 1];
    float s[8] = {0.f, 0.f, 0.f, 0.f, 0.f, 0.f, 0.f, 0.f};
    for (int n = n0 + sub; n < n1; n += 8) {
        uint4 v = e4[(size_t)n * row_u4 + t];
        s[0] += bf2f(v.x & 0xffff); s[1] += bf2f(v.x >> 16);
        s[2] += bf2f(v.y & 0xffff); s[3] += bf2f(v.y >> 16);
        s[4] += bf2f(v.z & 0xffff); s[5] += bf2f(v.z >> 16);
        s[6] += bf2f(v.w & 0xffff); s[7] += bf2f(v.w >> 16);
    }
    float4* p4 = (float4*)&part[(size_t)blockIdx.x * EMB + t * 8];
    p4[0] = (float4){s[0], s[1], s[2], s[3]};
    p4[1] = (float4){s[4], s[5], s[6], s[7]};
}

__global__ __launch_bounds__(128) void pool_fin(const float* __restrict__ part,
                                                unsigned short* __restrict__ pooled,
                                                int EMB) {
    int idx = blockIdx.x * 128 + threadIdx.x;   // over G*EMB
    int g = idx / EMB, c = idx - g * EMB;
    float s = 0.f;
#pragma unroll
    for (int sub = 0; sub < 8; sub++)
        s += part[(size_t)(g * 8 + sub) * EMB + c];
    pooled[idx] = f2bf(s);
}

// ---------------- post MLP via MFMA ----------------
__global__ __launch_bounds__(256) void post_mfma(const unsigned short* __restrict__ pooled,
                                                 const unsigned short* __restrict__ w1t,
                                                 const float* __restrict__ b1,
                                                 const unsigned short* __restrict__ w2t,
                                                 const float* __restrict__ b2,
                                                 float* __restrict__ out, int EMB) {
    __shared__ __align__(16) char lds[128 * 256];
    int t = threadIdx.x;
    int wave = t >> 6, lane = t & 63, l15 = lane & 15, l4 = lane >> 4;
    int wrow = wave * 32;
    f32x4 acc[2][8];
#pragma unroll
    for (int rt = 0; rt < 2; rt++)
#pragma unroll
        for (int ct = 0; ct < 8; ct++) acc[rt][ct] = (f32x4){0.f, 0.f, 0.f, 0.f};
    int r0 = wrow + l15, r1 = r0 + 16;
#pragma unroll 4
    for (int kk = 0; kk < EMB / 32; kk++) {
        int k0 = kk * 32 + l4 * 8;
        bf16x8 a0 = *(const bf16x8*)&pooled[(size_t)r0 * EMB + k0];
        bf16x8 a1 = *(const bf16x8*)&pooled[(size_t)r1 * EMB + k0];
#pragma unroll
        for (int ct = 0; ct < 8; ct++) {
            bf16x8 b = *(const bf16x8*)&w1t[(size_t)(ct * 16 + l15) * EMB + k0];
            acc[0][ct] = __builtin_amdgcn_mfma_f32_16x16x32_bf16(a0, b, acc[0][ct], 0, 0, 0);
            acc[1][ct] = __builtin_amdgcn_mfma_f32_16x16x32_bf16(a1, b, acc[1][ct], 0, 0, 0);
        }
    }
#pragma unroll
    for (int ct = 0; ct < 8; ct++) {
        int col = ct * 16 + l15;
        float bc = b1[col];
#pragma unroll
        for (int rt = 0; rt < 2; rt++)
#pragma unroll
            for (int j = 0; j < 4; j++) {
                int r = wrow + rt * 16 + l4 * 4 + j;
                float v = fmaxf(acc[rt][ct][j] + bc, 0.f);
                *(unsigned short*)(lds + r * 256 + ((col * 2) ^ ((r & 7) << 4))) = f2bf(v);
            }
    }
    __syncthreads();
#pragma unroll
    for (int rt = 0; rt < 2; rt++)
#pragma unroll
        for (int ct = 0; ct < 8; ct++) acc[rt][ct] = (f32x4){0.f, 0.f, 0.f, 0.f};
#pragma unroll
    for (int kk = 0; kk < 4; kk++) {
        int k0 = kk * 32 + l4 * 8;
        bf16x8 a0 = *(const bf16x8*)(lds + r0 * 256 + ((k0 * 2) ^ ((r0 & 7) << 4)));
        bf16x8 a1 = *(const bf16x8*)(lds + r1 * 256 + ((k0 * 2) ^ ((r1 & 7) << 4)));
#pragma unroll
        for (int ct = 0; ct < 8; ct++) {
            bf16x8 b = *(const bf16x8*)&w2t[(size_t)(ct * 16 + l15) * HID + k0];
            acc[0][ct] = __builtin_amdgcn_mfma_f32_16x16x32_bf16(a0, b, acc[0][ct], 0, 0, 0);
            acc[1][ct] = __builtin_amdgcn_mfma_f32_16x16x32_bf16(a1, b, acc[1][ct], 0, 0, 0);
        }
    }
#pragma unroll
    for (int ct = 0; ct < 8; ct++) {
        int col = ct * 16 + l15;
        float bc = b2[col];
#pragma unroll
        for (int rt = 0; rt < 2; rt++)
#pragma unroll
            for (int j = 0; j < 4; j++) {
                int r = wrow + rt * 16 + l4 * 4 + j;
                out[(size_t)r * HID + col] = acc[rt][ct][j] + bc;
            }
    }
}

// ---------------- launch ----------------

extern "C" void kernel_launch(void* const* d_in, const int* in_sizes, int n_in,
                              void* d_out, int out_size, void* d_ws, size_t ws_size,
                              hipStream_t stream) {
    const float* x       = (const float*)d_in[0];
    const int* edge_index= (const int*)d_in[1];
    const int* batch     = (const int*)d_in[2];
    const float* pre_w   = (const float*)d_in[3];
    const float* pre_b   = (const float*)d_in[4];
    const float* conv_w1 = (const float*)d_in[5];
    const float* conv_b1 = (const float*)d_in[6];
    const float* conv_w2 = (const float*)d_in[7];
    const float* conv_b2 = (const float*)d_in[8];
    const float* post_w1 = (const float*)d_in[9];
    const float* post_b1 = (const float*)d_in[10];
    const float* post_w2 = (const float*)d_in[11];
    const float* post_b2 = (const float*)d_in[12];
    float* outp = (float*)d_out;

    int N = in_sizes[0] / HID;
    int E = in_sizes[1] / 2;
    int L = in_sizes[5] / (HID * HID);
    int G = out_size / HID;
    int EMB = (L + 1) * HID;

    const int* src = edge_index;
    const int* dst = edge_index + E;

    char* w = (char*)d_ws;
    auto alloc = [&](size_t bytes) -> char* {
        char* p = w;
        w += (bytes + 255) & ~(size_t)255;
        return p;
    };
    unsigned short* emb   = (unsigned short*)alloc((size_t)N * EMB * 2);     // all layer embeddings
    unsigned short* z_bf  = (unsigned short*)alloc((size_t)N * HID * 2);     // also used as x_bf
    unsigned short* xres  = (unsigned short*)alloc((size_t)N * HID * 2);     // bf16 residual
    float* part   = (float*)alloc((size_t)G * 8 * EMB * 4);
    unsigned short* pooled = (unsigned short*)alloc((size_t)G * EMB * 2);
    unsigned short* Wt_pre = (unsigned short*)alloc((size_t)HID * HID * 2);
    unsigned short* Wt_c1  = (unsigned short*)alloc((size_t)L * HID * HID * 2);
    unsigned short* Wt_c2  = (unsigned short*)alloc((size_t)L * HID * HID * 2);
    unsigned short* w1t    = (unsigned short*)alloc((size_t)EMB * HID * 2);
    unsigned short* w2t    = (unsigned short*)alloc((size_t)HID * HID * 2);
    int* deg      = (int*)alloc((size_t)(N + 1) * 4);
    int* row_ptr  = (int*)alloc((size_t)(N + 1) * 4);
    int* pos      = (int*)alloc((size_t)(N + 1) * 4);
    int* bsum     = (int*)alloc((size_t)1024 * 4);
    int* bstart   = (int*)alloc((size_t)1024 * 4);
    int* csr_src  = (int*)alloc((size_t)E * 4);
    int* gstart   = (int*)alloc((size_t)(G + 1) * 4);
    (void)ws_size; (void)n_in;

    int eb = (E + 255) / 256;
    int nb = (N + 255) / 256;

    // CSR by dst
    zero_i32<<<nb, 256, 0, stream>>>(deg, N);
    count_deg<<<eb, 256, 0, stream>>>(dst, deg, E);
    block_sums<<<nb, 256, 0, stream>>>(deg, bsum, N);
    scan_bsums<<<1, 1024, 0, stream>>>(bsum, bstart, nb);
    scan_within<<<nb, 256, 0, stream>>>(deg, bstart, row_ptr, pos, N);
    fill_csr<<<eb, 256, 0, stream>>>(src, dst, pos, csr_src, E);
    graph_starts<<<1, 256, 0, stream>>>(batch, gstart, N, G);

    // conversions / transposes (x_bf aliases z_bf; consumed by linear_pre before agg runs)
    f32_to_bf16_vec<<<(N * HID / 8 + 255) / 256, 256, 0, stream>>>(x, z_bf, N * HID / 8);
    transpose_kc<<<(HID * HID + 255) / 256, 256, 0, stream>>>(pre_w, Wt_pre, HID, HID, HID * HID);
    transpose_kc<<<(L * HID * HID + 255) / 256, 256, 0, stream>>>(conv_w1, Wt_c1, HID, HID, L * HID * HID);
    transpose_kc<<<(L * HID * HID + 255) / 256, 256, 0, stream>>>(conv_w2, Wt_c2, HID, HID, L * HID * HID);
    transpose_kc<<<(EMB * HID + 255) / 256, 256, 0, stream>>>(post_w1, w1t, EMB, HID, EMB * HID);
    transpose_kc<<<(HID * HID + 255) / 256, 256, 0, stream>>>(post_w2, w2t, HID, HID, HID * HID);

    int gb64 = (N + 63) / 64;
    int gb16 = (N + 15) / 16;

    // pre linear: emb slice0 = x@pre_w + pre_b (no relu) ; xres = same (bf16)
    linear_pre<<<gb64, 256, 0, stream>>>(z_bf, Wt_pre, pre_b, emb, EMB, xres, N);

    for (int i = 0; i < L; i++) {
        agg_kernel<<<gb16, 256, 0, stream>>>(emb, i * 16, EMB / 8, row_ptr, csr_src, z_bf, N);
        unsigned short* slice_out = emb + (size_t)(i + 1) * HID;
        if (i & 1) {
            fused_gemm12<true><<<gb16, 128, 0, stream>>>(
                z_bf, Wt_c1 + (size_t)i * HID * HID, conv_b1 + i * HID,
                Wt_c2 + (size_t)i * HID * HID, conv_b2 + i * HID, xres, slice_out, EMB, N);
        } else {
            fused_gemm12<false><<<gb16, 128, 0, stream>>>(
                z_bf, Wt_c1 + (size_t)i * HID * HID, conv_b1 + i * HID,
                Wt_c2 + (size_t)i * HID * HID, conv_b2 + i * HID, xres, slice_out, EMB, N);
        }
    }

    pool_all<<<G * 8, 128, 0, stream>>>(emb, gstart, part, EMB);
    pool_fin<<<(G * EMB) / 128, 128, 0, stream>>>(part, pooled, EMB);
    post_mfma<<<1, 256, 0, stream>>>(pooled, w1t, post_b1, w2t, post_b2, outp, EMB);
}

// Round 8
// 581.969 us; speedup vs baseline: 1.5130x; 1.0076x over previous
//
#include <hip/hip_runtime.h>
#include <hip/hip_bf16.h>

#define HID 128

using bf16x8 = __attribute__((ext_vector_type(8))) short;
using f32x4  = __attribute__((ext_vector_type(4))) float;

__device__ inline float bf2f(unsigned int u16) {
    union { float f; unsigned int i; } v; v.i = u16 << 16; return v.f;
}
__device__ inline unsigned short f2bf(float f) {
    __hip_bfloat16 h = __float2bfloat16(f);        // RNE
    return *reinterpret_cast<unsigned short*>(&h);
}

// ---------------- CSR build ----------------

__global__ void zero_i32(int* __restrict__ p, int n) {
    int i = blockIdx.x * blockDim.x + threadIdx.x;
    if (i < n) p[i] = 0;
}

__global__ void count_deg(const int* __restrict__ dst, int* __restrict__ deg, int E) {
    int e = blockIdx.x * blockDim.x + threadIdx.x;
    if (e < E) atomicAdd(&deg[dst[e]], 1);
}

__global__ __launch_bounds__(256) void block_sums(const int* __restrict__ deg,
                                                  int* __restrict__ bsum, int n) {
    __shared__ int red[256];
    int t = threadIdx.x;
    int i = blockIdx.x * 256 + t;
    red[t] = (i < n) ? deg[i] : 0;
    __syncthreads();
    for (int off = 128; off > 0; off >>= 1) {
        if (t < off) red[t] += red[t + off];
        __syncthreads();
    }
    if (t == 0) bsum[blockIdx.x] = red[0];
}

__global__ __launch_bounds__(1024) void scan_bsums(const int* __restrict__ bsum,
                                                   int* __restrict__ bstart, int nb) {
    __shared__ int s[1024];
    int t = threadIdx.x;
    s[t] = (t < nb) ? bsum[t] : 0;
    __syncthreads();
    for (int off = 1; off < 1024; off <<= 1) {
        int v = (t >= off) ? s[t - off] : 0;
        __syncthreads();
        s[t] += v;
        __syncthreads();
    }
    if (t < nb) bstart[t] = (t == 0) ? 0 : s[t - 1];
}

__global__ __launch_bounds__(256) void scan_within(const int* __restrict__ deg,
                                                   const int* __restrict__ bstart,
                                                   int* __restrict__ row_ptr,
                                                   int* __restrict__ pos, int n) {
    __shared__ int s[256];
    int b = blockIdx.x, t = threadIdx.x;
    int i = b * 256 + t;
    int v = (i < n) ? deg[i] : 0;
    s[t] = v;
    __syncthreads();
    for (int off = 1; off < 256; off <<= 1) {
        int u = (t >= off) ? s[t - off] : 0;
        __syncthreads();
        s[t] += u;
        __syncthreads();
    }
    if (i < n) {
        int excl = bstart[b] + s[t] - v;
        row_ptr[i] = excl;
        pos[i] = excl;
        if (i == n - 1) row_ptr[n] = bstart[b] + s[t];
    }
}

__global__ void fill_csr(const int* __restrict__ src, const int* __restrict__ dst,
                         int* __restrict__ pos, int* __restrict__ csr_src, int E) {
    int e = blockIdx.x * blockDim.x + threadIdx.x;
    if (e < E) {
        int p = atomicAdd(&pos[dst[e]], 1);
        csr_src[p] = src[e];
    }
}

__global__ void graph_starts(const int* __restrict__ batch, int* __restrict__ gstart,
                             int n, int G) {
    int g = blockIdx.x * blockDim.x + threadIdx.x;
    if (g > G) return;
    int lo = 0, hi = n;
    while (lo < hi) { int m = (lo + hi) >> 1; if (batch[m] < g) lo = m + 1; else hi = m; }
    gstart[g] = lo;
}

// ---------------- conversions ----------------

__global__ void f32_to_bf16_vec(const float* __restrict__ in,
                                unsigned short* __restrict__ out, int n8) {
    int i = blockIdx.x * blockDim.x + threadIdx.x;
    if (i >= n8) return;
    const float4* in4 = (const float4*)in;
    float4 a = in4[i * 2], b = in4[i * 2 + 1];
    uint4 o;
    o.x = f2bf(a.x) | ((unsigned)f2bf(a.y) << 16);
    o.y = f2bf(a.z) | ((unsigned)f2bf(a.w) << 16);
    o.z = f2bf(b.x) | ((unsigned)f2bf(b.y) << 16);
    o.w = f2bf(b.z) | ((unsigned)f2bf(b.w) << 16);
    ((uint4*)out)[i] = o;
}

// W[mat][k][c] fp32 -> Wt[mat][c][k] bf16
__global__ void transpose_kc(const float* __restrict__ W, unsigned short* __restrict__ Wt,
                             int K, int C, int total) {
    int tid = blockIdx.x * blockDim.x + threadIdx.x;
    if (tid >= total) return;
    int kc = K * C;
    int mat = tid / kc;
    int rem = tid - mat * kc;
    int c = rem / K;
    int k = rem - c * K;
    Wt[tid] = f2bf(W[(size_t)mat * kc + (size_t)k * C + c]);
}

// ---------------- fused GIN layer (gather + MLP), col-split ----------------
// block = 128 thr = 2 waves, 16 node rows.
// Phase G: gather z = h + sum(h[src]) -> swizzled LDS zt (8 lanes/node x 2 uint4 chains).
// Phase 1: GEMM1 A from zt; wave w computes cols [w*64,w*64+64); relu -> tt.
// Phase 2: GEMM2 A from tt (K=128); +b2 [,+xres bf16]; emb slice = relu.
template <bool ODD>
__global__ __launch_bounds__(128) void fused_layer(const unsigned short* __restrict__ emb,
                                                   int slice_u4, int row_u4,
                                                   const int* __restrict__ row_ptr,
                                                   const int* __restrict__ csr_src,
                                                   const unsigned short* __restrict__ Wt1,
                                                   const float* __restrict__ b1,
                                                   const unsigned short* __restrict__ Wt2,
                                                   const float* __restrict__ b2,
                                                   unsigned short* __restrict__ xres,
                                                   unsigned short* __restrict__ h_out,
                                                   int out_stride, int N) {
    __shared__ __align__(16) char zt[16 * 256];    // z tile bf16, XOR-swizzled
    __shared__ __align__(16) char tt[16 * 256];    // t tile bf16, XOR-swizzled
    int t = threadIdx.x;
    int rowbase = blockIdx.x * 16;

    // ---- gather ----
    {
        int nl = t >> 3;                 // local node 0..15
        int lane8 = t & 7;               // chunk lanes: lane8 and lane8+8
        int node = rowbase + nl;
        const uint4* h4 = (const uint4*)emb;
        float sa0=0,sa1=0,sa2=0,sa3=0,sa4=0,sa5=0,sa6=0,sa7=0;
        float sb0=0,sb1=0,sb2=0,sb3=0,sb4=0,sb5=0,sb6=0,sb7=0;
        if (node < N) {
            size_t base = (size_t)node * row_u4 + slice_u4;
            uint4 u0 = h4[base + lane8];
            uint4 u1 = h4[base + lane8 + 8];
            sa0 = bf2f(u0.x & 0xffff); sa1 = bf2f(u0.x >> 16);
            sa2 = bf2f(u0.y & 0xffff); sa3 = bf2f(u0.y >> 16);
            sa4 = bf2f(u0.z & 0xffff); sa5 = bf2f(u0.z >> 16);
            sa6 = bf2f(u0.w & 0xffff); sa7 = bf2f(u0.w >> 16);
            sb0 = bf2f(u1.x & 0xffff); sb1 = bf2f(u1.x >> 16);
            sb2 = bf2f(u1.y & 0xffff); sb3 = bf2f(u1.y >> 16);
            sb4 = bf2f(u1.z & 0xffff); sb5 = bf2f(u1.z >> 16);
            sb6 = bf2f(u1.w & 0xffff); sb7 = bf2f(u1.w >> 16);
            int e0 = row_ptr[node], e1 = row_ptr[node + 1];
            int e = e0;
            for (; e + 1 < e1; e += 2) {
                int n0 = csr_src[e], n1 = csr_src[e + 1];
                size_t p0 = (size_t)n0 * row_u4 + slice_u4;
                size_t p1 = (size_t)n1 * row_u4 + slice_u4;
                uint4 v0 = h4[p0 + lane8];
                uint4 v1 = h4[p0 + lane8 + 8];
                uint4 w0 = h4[p1 + lane8];
                uint4 w1 = h4[p1 + lane8 + 8];
                sa0 += bf2f(v0.x & 0xffff); sa1 += bf2f(v0.x >> 16);
                sa2 += bf2f(v0.y & 0xffff); sa3 += bf2f(v0.y >> 16);
                sa4 += bf2f(v0.z & 0xffff); sa5 += bf2f(v0.z >> 16);
                sa6 += bf2f(v0.w & 0xffff); sa7 += bf2f(v0.w >> 16);
                sb0 += bf2f(v1.x & 0xffff); sb1 += bf2f(v1.x >> 16);
                sb2 += bf2f(v1.y & 0xffff); sb3 += bf2f(v1.y >> 16);
                sb4 += bf2f(v1.z & 0xffff); sb5 += bf2f(v1.z >> 16);
                sb6 += bf2f(v1.w & 0xffff); sb7 += bf2f(v1.w >> 16);
                sa0 += bf2f(w0.x & 0xffff); sa1 += bf2f(w0.x >> 16);
                sa2 += bf2f(w0.y & 0xffff); sa3 += bf2f(w0.y >> 16);
                sa4 += bf2f(w0.z & 0xffff); sa5 += bf2f(w0.z >> 16);
                sa6 += bf2f(w0.w & 0xffff); sa7 += bf2f(w0.w >> 16);
                sb0 += bf2f(w1.x & 0xffff); sb1 += bf2f(w1.x >> 16);
                sb2 += bf2f(w1.y & 0xffff); sb3 += bf2f(w1.y >> 16);
                sb4 += bf2f(w1.z & 0xffff); sb5 += bf2f(w1.z >> 16);
                sb6 += bf2f(w1.w & 0xffff); sb7 += bf2f(w1.w >> 16);
            }
            if (e < e1) {
                size_t p0 = (size_t)csr_src[e] * row_u4 + slice_u4;
                uint4 v0 = h4[p0 + lane8];
                uint4 v1 = h4[p0 + lane8 + 8];
                sa0 += bf2f(v0.x & 0xffff); sa1 += bf2f(v0.x >> 16);
                sa2 += bf2f(v0.y & 0xffff); sa3 += bf2f(v0.y >> 16);
                sa4 += bf2f(v0.z & 0xffff); sa5 += bf2f(v0.z >> 16);
                sa6 += bf2f(v0.w & 0xffff); sa7 += bf2f(v0.w >> 16);
                sb0 += bf2f(v1.x & 0xffff); sb1 += bf2f(v1.x >> 16);
                sb2 += bf2f(v1.y & 0xffff); sb3 += bf2f(v1.y >> 16);
                sb4 += bf2f(v1.z & 0xffff); sb5 += bf2f(v1.z >> 16);
                sb6 += bf2f(v1.w & 0xffff); sb7 += bf2f(v1.w >> 16);
            }
        }
        uint4 oa, ob;
        oa.x = f2bf(sa0) | ((unsigned)f2bf(sa1) << 16);
        oa.y = f2bf(sa2) | ((unsigned)f2bf(sa3) << 16);
        oa.z = f2bf(sa4) | ((unsigned)f2bf(sa5) << 16);
        oa.w = f2bf(sa6) | ((unsigned)f2bf(sa7) << 16);
        ob.x = f2bf(sb0) | ((unsigned)f2bf(sb1) << 16);
        ob.y = f2bf(sb2) | ((unsigned)f2bf(sb3) << 16);
        ob.z = f2bf(sb4) | ((unsigned)f2bf(sb5) << 16);
        ob.w = f2bf(sb6) | ((unsigned)f2bf(sb7) << 16);
        int swz = (nl & 7) << 4;
        *(uint4*)(zt + nl * 256 + ((lane8 * 16) ^ swz)) = oa;
        *(uint4*)(zt + nl * 256 + (((lane8 + 8) * 16) ^ swz)) = ob;
    }
    __syncthreads();

    int wave = t >> 6, lane = t & 63, l15 = lane & 15, l4 = lane >> 4;
    int colbase = wave * 64;

    f32x4 acc[4];
#pragma unroll
    for (int ct = 0; ct < 4; ct++) acc[ct] = (f32x4){0.f, 0.f, 0.f, 0.f};

    // ---- GEMM1: A from zt ----
#pragma unroll
    for (int kk = 0; kk < 4; kk++) {
        int k0 = kk * 32 + l4 * 8;
        bf16x8 a0 = *(const bf16x8*)(zt + l15 * 256 + ((k0 * 2) ^ ((l15 & 7) << 4)));
#pragma unroll
        for (int ct = 0; ct < 4; ct++) {
            bf16x8 b = *(const bf16x8*)&Wt1[(size_t)(colbase + ct * 16 + l15) * HID + k0];
            acc[ct] = __builtin_amdgcn_mfma_f32_16x16x32_bf16(a0, b, acc[ct], 0, 0, 0);
        }
    }

    // ---- epilogue1: relu(acc+b1) -> tt (this wave's 64 cols) ----
#pragma unroll
    for (int ct = 0; ct < 4; ct++) {
        int col = colbase + ct * 16 + l15;
        float bc = b1[col];
#pragma unroll
        for (int j = 0; j < 4; j++) {
            int r = l4 * 4 + j;                     // rows 0..15
            float v = fmaxf(acc[ct][j] + bc, 0.f);
            *(unsigned short*)(tt + r * 256 + ((col * 2) ^ ((r & 7) << 4))) = f2bf(v);
        }
    }
    __syncthreads();

    // ---- GEMM2: A from full tt (K=128), this wave's 64 output cols ----
#pragma unroll
    for (int ct = 0; ct < 4; ct++) acc[ct] = (f32x4){0.f, 0.f, 0.f, 0.f};
#pragma unroll
    for (int kk = 0; kk < 4; kk++) {
        int k0 = kk * 32 + l4 * 8;
        bf16x8 a0 = *(const bf16x8*)(tt + l15 * 256 + ((k0 * 2) ^ ((l15 & 7) << 4)));
#pragma unroll
        for (int ct = 0; ct < 4; ct++) {
            bf16x8 b = *(const bf16x8*)&Wt2[(size_t)(colbase + ct * 16 + l15) * HID + k0];
            acc[ct] = __builtin_amdgcn_mfma_f32_16x16x32_bf16(a0, b, acc[ct], 0, 0, 0);
        }
    }

    // ---- epilogue2: +b2 [,+xres bf16], emb slice = relu ----
#pragma unroll
    for (int ct = 0; ct < 4; ct++) {
        int col = colbase + ct * 16 + l15;
        float bc = b2[col];
#pragma unroll
        for (int j = 0; j < 4; j++) {
            int r = l4 * 4 + j;
            int rg = rowbase + r;
            if (rg < N) {
                float v = acc[ct][j] + bc;
                if (ODD) {
                    v += bf2f(xres[(size_t)rg * HID + col]);
                    xres[(size_t)rg * HID + col] = f2bf(v);
                }
                h_out[(size_t)rg * out_stride + col] = f2bf(fmaxf(v, 0.f));
            }
        }
    }
}

// ---------------- pre linear (MFMA, global in, writes emb slice 0 + xres bf16) ----------------
__global__ __launch_bounds__(256) void linear_pre(const unsigned short* __restrict__ in,
                                                  const unsigned short* __restrict__ Wt,
                                                  const float* __restrict__ bias,
                                                  unsigned short* __restrict__ out,
                                                  int out_stride,
                                                  unsigned short* __restrict__ pre_out, int M) {
    int tid = threadIdx.x;
    int wave = tid >> 6, lane = tid & 63;
    int l15 = lane & 15, l4 = lane >> 4;
    int rowbase = blockIdx.x * 64 + wave * 16;
    f32x4 acc[8];
#pragma unroll
    for (int ct = 0; ct < 8; ct++) acc[ct] = (f32x4){0.f, 0.f, 0.f, 0.f};
    int r0 = min(rowbase + l15, M - 1);
#pragma unroll
    for (int kk = 0; kk < 4; kk++) {
        int k0 = kk * 32 + l4 * 8;
        bf16x8 a0 = *(const bf16x8*)&in[(size_t)r0 * HID + k0];
#pragma unroll
        for (int ct = 0; ct < 8; ct++) {
            bf16x8 b = *(const bf16x8*)&Wt[(size_t)(ct * 16 + l15) * HID + k0];
            acc[ct] = __builtin_amdgcn_mfma_f32_16x16x32_bf16(a0, b, acc[ct], 0, 0, 0);
        }
    }
#pragma unroll
    for (int ct = 0; ct < 8; ct++) {
        int col = ct * 16 + l15;
        float bc = bias[col];
#pragma unroll
        for (int j = 0; j < 4; j++) {
            int r = rowbase + l4 * 4 + j;
            if (r < M) {
                float v = acc[ct][j] + bc;
                unsigned short bv = f2bf(v);
                pre_out[(size_t)r * HID + col] = bv;          // xres bf16
                out[(size_t)r * out_stride + col] = bv;       // emb slice 0 (no relu)
            }
        }
    }
}

// ---------------- pooling over full emb, 2-level deterministic ----------------
__global__ __launch_bounds__(128) void pool_all(const unsigned short* __restrict__ emb,
                                                const int* __restrict__ gstart,
                                                float* __restrict__ part, int EMB) {
    int g = blockIdx.x >> 3, sub = blockIdx.x & 7;
    int t = threadIdx.x;
    if (t >= 112) return;
    const uint4* e4 = (const uint4*)emb;     // row stride EMB/8 = 112 uint4
    int row_u4 = EMB / 8;
    int n0 = gstart[g], n1 = gstart[g + 1];
    float s[8] = {0.f, 0.f, 0.f, 0.f, 0.f, 0.f, 0.f, 0.f};
    for (int n = n0 + sub; n < n1; n += 8) {
        uint4 v = e4[(size_t)n * row_u4 + t];
        s[0] += bf2f(v.x & 0xffff); s[1] += bf2f(v.x >> 16);
        s[2] += bf2f(v.y & 0xffff); s[3] += bf2f(v.y >> 16);
        s[4] += bf2f(v.z & 0xffff); s[5] += bf2f(v.z >> 16);
        s[6] += bf2f(v.w & 0xffff); s[7] += bf2f(v.w >> 16);
    }
    float4* p4 = (float4*)&part[(size_t)blockIdx.x * EMB + t * 8];
    p4[0] = (float4){s[0], s[1], s[2], s[3]};
    p4[1] = (float4){s[4], s[5], s[6], s[7]};
}

__global__ __launch_bounds__(128) void pool_fin(const float* __restrict__ part,
                                                unsigned short* __restrict__ pooled,
                                                int EMB) {
    int idx = blockIdx.x * 128 + threadIdx.x;   // over G*EMB
    int g = idx / EMB, c = idx - g * EMB;
    float s = 0.f;
#pragma unroll
    for (int sub = 0; sub < 8; sub++)
        s += part[(size_t)(g * 8 + sub) * EMB + c];
    pooled[idx] = f2bf(s);
}

// ---------------- post MLP via MFMA ----------------
__global__ __launch_bounds__(256) void post_mfma(const unsigned short* __restrict__ pooled,
                                                 const unsigned short* __restrict__ w1t,
                                                 const float* __restrict__ b1,
                                                 const unsigned short* __restrict__ w2t,
                                                 const float* __restrict__ b2,
                                                 float* __restrict__ out, int EMB) {
    __shared__ __align__(16) char lds[128 * 256];
    int t = threadIdx.x;
    int wave = t >> 6, lane = t & 63, l15 = lane & 15, l4 = lane >> 4;
    int wrow = wave * 32;
    f32x4 acc[2][8];
#pragma unroll
    for (int rt = 0; rt < 2; rt++)
#pragma unroll
        for (int ct = 0; ct < 8; ct++) acc[rt][ct] = (f32x4){0.f, 0.f, 0.f, 0.f};
    int r0 = wrow + l15, r1 = r0 + 16;
#pragma unroll 4
    for (int kk = 0; kk < EMB / 32; kk++) {
        int k0 = kk * 32 + l4 * 8;
        bf16x8 a0 = *(const bf16x8*)&pooled[(size_t)r0 * EMB + k0];
        bf16x8 a1 = *(const bf16x8*)&pooled[(size_t)r1 * EMB + k0];
#pragma unroll
        for (int ct = 0; ct < 8; ct++) {
            bf16x8 b = *(const bf16x8*)&w1t[(size_t)(ct * 16 + l15) * EMB + k0];
            acc[0][ct] = __builtin_amdgcn_mfma_f32_16x16x32_bf16(a0, b, acc[0][ct], 0, 0, 0);
            acc[1][ct] = __builtin_amdgcn_mfma_f32_16x16x32_bf16(a1, b, acc[1][ct], 0, 0, 0);
        }
    }
#pragma unroll
    for (int ct = 0; ct < 8; ct++) {
        int col = ct * 16 + l15;
        float bc = b1[col];
#pragma unroll
        for (int rt = 0; rt < 2; rt++)
#pragma unroll
            for (int j = 0; j < 4; j++) {
                int r = wrow + rt * 16 + l4 * 4 + j;
                float v = fmaxf(acc[rt][ct][j] + bc, 0.f);
                *(unsigned short*)(lds + r * 256 + ((col * 2) ^ ((r & 7) << 4))) = f2bf(v);
            }
    }
    __syncthreads();
#pragma unroll
    for (int rt = 0; rt < 2; rt++)
#pragma unroll
        for (int ct = 0; ct < 8; ct++) acc[rt][ct] = (f32x4){0.f, 0.f, 0.f, 0.f};
#pragma unroll
    for (int kk = 0; kk < 4; kk++) {
        int k0 = kk * 32 + l4 * 8;
        bf16x8 a0 = *(const bf16x8*)(lds + r0 * 256 + ((k0 * 2) ^ ((r0 & 7) << 4)));
        bf16x8 a1 = *(const bf16x8*)(lds + r1 * 256 + ((k0 * 2) ^ ((r1 & 7) << 4)));
#pragma unroll
        for (int ct = 0; ct < 8; ct++) {
            bf16x8 b = *(const bf16x8*)&w2t[(size_t)(ct * 16 + l15) * HID + k0];
            acc[0][ct] = __builtin_amdgcn_mfma_f32_16x16x32_bf16(a0, b, acc[0][ct], 0, 0, 0);
            acc[1][ct] = __builtin_amdgcn_mfma_f32_16x16x32_bf16(a1, b, acc[1][ct], 0, 0, 0);
        }
    }
#pragma unroll
    for (int ct = 0; ct < 8; ct++) {
        int col = ct * 16 + l15;
        float bc = b2[col];
#pragma unroll
        for (int rt = 0; rt < 2; rt++)
#pragma unroll
            for (int j = 0; j < 4; j++) {
                int r = wrow + rt * 16 + l4 * 4 + j;
                out[(size_t)r * HID + col] = acc[rt][ct][j] + bc;
            }
    }
}

// ---------------- launch ----------------

extern "C" void kernel_launch(void* const* d_in, const int* in_sizes, int n_in,
                              void* d_out, int out_size, void* d_ws, size_t ws_size,
                              hipStream_t stream) {
    const float* x       = (const float*)d_in[0];
    const int* edge_index= (const int*)d_in[1];
    const int* batch     = (const int*)d_in[2];
    const float* pre_w   = (const float*)d_in[3];
    const float* pre_b   = (const float*)d_in[4];
    const float* conv_w1 = (const float*)d_in[5];
    const float* conv_b1 = (const float*)d_in[6];
    const float* conv_w2 = (const float*)d_in[7];
    const float* conv_b2 = (const float*)d_in[8];
    const float* post_w1 = (const float*)d_in[9];
    const float* post_b1 = (const float*)d_in[10];
    const float* post_w2 = (const float*)d_in[11];
    const float* post_b2 = (const float*)d_in[12];
    float* outp = (float*)d_out;

    int N = in_sizes[0] / HID;
    int E = in_sizes[1] / 2;
    int L = in_sizes[5] / (HID * HID);
    int G = out_size / HID;
    int EMB = (L + 1) * HID;

    const int* src = edge_index;
    const int* dst = edge_index + E;

    char* w = (char*)d_ws;
    auto alloc = [&](size_t bytes) -> char* {
        char* p = w;
        w += (bytes + 255) & ~(size_t)255;
        return p;
    };
    unsigned short* emb   = (unsigned short*)alloc((size_t)N * EMB * 2);     // all layer embeddings
    unsigned short* x_bf  = (unsigned short*)alloc((size_t)N * HID * 2);
    unsigned short* xres  = (unsigned short*)alloc((size_t)N * HID * 2);     // bf16 residual
    float* part   = (float*)alloc((size_t)G * 8 * EMB * 4);
    unsigned short* pooled = (unsigned short*)alloc((size_t)G * EMB * 2);
    unsigned short* Wt_pre = (unsigned short*)alloc((size_t)HID * HID * 2);
    unsigned short* Wt_c1  = (unsigned short*)alloc((size_t)L * HID * HID * 2);
    unsigned short* Wt_c2  = (unsigned short*)alloc((size_t)L * HID * HID * 2);
    unsigned short* w1t    = (unsigned short*)alloc((size_t)EMB * HID * 2);
    unsigned short* w2t    = (unsigned short*)alloc((size_t)HID * HID * 2);
    int* deg      = (int*)alloc((size_t)(N + 1) * 4);
    int* row_ptr  = (int*)alloc((size_t)(N + 1) * 4);
    int* pos      = (int*)alloc((size_t)(N + 1) * 4);
    int* bsum     = (int*)alloc((size_t)1024 * 4);
    int* bstart   = (int*)alloc((size_t)1024 * 4);
    int* csr_src  = (int*)alloc((size_t)E * 4);
    int* gstart   = (int*)alloc((size_t)(G + 1) * 4);
    (void)ws_size; (void)n_in;

    int eb = (E + 255) / 256;
    int nb = (N + 255) / 256;

    // CSR by dst
    zero_i32<<<nb, 256, 0, stream>>>(deg, N);
    count_deg<<<eb, 256, 0, stream>>>(dst, deg, E);
    block_sums<<<nb, 256, 0, stream>>>(deg, bsum, N);
    scan_bsums<<<1, 1024, 0, stream>>>(bsum, bstart, nb);
    scan_within<<<nb, 256, 0, stream>>>(deg, bstart, row_ptr, pos, N);
    fill_csr<<<eb, 256, 0, stream>>>(src, dst, pos, csr_src, E);
    graph_starts<<<1, 256, 0, stream>>>(batch, gstart, N, G);

    // conversions / transposes
    f32_to_bf16_vec<<<(N * HID / 8 + 255) / 256, 256, 0, stream>>>(x, x_bf, N * HID / 8);
    transpose_kc<<<(HID * HID + 255) / 256, 256, 0, stream>>>(pre_w, Wt_pre, HID, HID, HID * HID);
    transpose_kc<<<(L * HID * HID + 255) / 256, 256, 0, stream>>>(conv_w1, Wt_c1, HID, HID, L * HID * HID);
    transpose_kc<<<(L * HID * HID + 255) / 256, 256, 0, stream>>>(conv_w2, Wt_c2, HID, HID, L * HID * HID);
    transpose_kc<<<(EMB * HID + 255) / 256, 256, 0, stream>>>(post_w1, w1t, EMB, HID, EMB * HID);
    transpose_kc<<<(HID * HID + 255) / 256, 256, 0, stream>>>(post_w2, w2t, HID, HID, HID * HID);

    int gb64 = (N + 63) / 64;
    int gb16 = (N + 15) / 16;

    // pre linear: emb slice0 = x@pre_w + pre_b (no relu) ; xres = same (bf16)
    linear_pre<<<gb64, 256, 0, stream>>>(x_bf, Wt_pre, pre_b, emb, EMB, xres, N);

    for (int i = 0; i < L; i++) {
        unsigned short* slice_out = emb + (size_t)(i + 1) * HID;
        if (i & 1) {
            fused_layer<true><<<gb16, 128, 0, stream>>>(
                emb, i * 16, EMB / 8, row_ptr, csr_src,
                Wt_c1 + (size_t)i * HID * HID, conv_b1 + i * HID,
                Wt_c2 + (size_t)i * HID * HID, conv_b2 + i * HID,
                xres, slice_out, EMB, N);
        } else {
            fused_layer<false><<<gb16, 128, 0, stream>>>(
                emb, i * 16, EMB / 8, row_ptr, csr_src,
                Wt_c1 + (size_t)i * HID * HID, conv_b1 + i * HID,
                Wt_c2 + (size_t)i * HID * HID, conv_b2 + i * HID,
                xres, slice_out, EMB, N);
        }
    }

    pool_all<<<G * 8, 128, 0, stream>>>(emb, gstart, part, EMB);
    pool_fin<<<(G * EMB) / 128, 128, 0, stream>>>(part, pooled, EMB);
    post_mfma<<<1, 256, 0, stream>>>(pooled, w1t, post_b1, w2t, post_b2, outp, EMB);
}

// Round 9
// 524.497 us; speedup vs baseline: 1.6788x; 1.1096x over previous
//
#include <hip/hip_runtime.h>
#include <hip/hip_bf16.h>

#define HID 128

using bf16x8 = __attribute__((ext_vector_type(8))) short;
using f32x4  = __attribute__((ext_vector_type(4))) float;

__device__ inline float bf2f(unsigned int u16) {
    union { float f; unsigned int i; } v; v.i = u16 << 16; return v.f;
}
__device__ inline unsigned short f2bf(float f) {
    __hip_bfloat16 h = __float2bfloat16(f);        // RNE
    return *reinterpret_cast<unsigned short*>(&h);
}

// ---------------- CSR build ----------------

__global__ void zero_i32(int* __restrict__ p, int n) {
    int i = blockIdx.x * blockDim.x + threadIdx.x;
    if (i < n) p[i] = 0;
}

__global__ void count_deg(const int* __restrict__ dst, int* __restrict__ deg, int E) {
    int e = blockIdx.x * blockDim.x + threadIdx.x;
    if (e < E) atomicAdd(&deg[dst[e]], 1);
}

__global__ __launch_bounds__(256) void block_sums(const int* __restrict__ deg,
                                                  int* __restrict__ bsum, int n) {
    __shared__ int red[256];
    int t = threadIdx.x;
    int i = blockIdx.x * 256 + t;
    red[t] = (i < n) ? deg[i] : 0;
    __syncthreads();
    for (int off = 128; off > 0; off >>= 1) {
        if (t < off) red[t] += red[t + off];
        __syncthreads();
    }
    if (t == 0) bsum[blockIdx.x] = red[0];
}

__global__ __launch_bounds__(1024) void scan_bsums(const int* __restrict__ bsum,
                                                   int* __restrict__ bstart, int nb) {
    __shared__ int s[1024];
    int t = threadIdx.x;
    s[t] = (t < nb) ? bsum[t] : 0;
    __syncthreads();
    for (int off = 1; off < 1024; off <<= 1) {
        int v = (t >= off) ? s[t - off] : 0;
        __syncthreads();
        s[t] += v;
        __syncthreads();
    }
    if (t < nb) bstart[t] = (t == 0) ? 0 : s[t - 1];
}

__global__ __launch_bounds__(256) void scan_within(const int* __restrict__ deg,
                                                   const int* __restrict__ bstart,
                                                   int* __restrict__ row_ptr,
                                                   int* __restrict__ pos, int n) {
    __shared__ int s[256];
    int b = blockIdx.x, t = threadIdx.x;
    int i = b * 256 + t;
    int v = (i < n) ? deg[i] : 0;
    s[t] = v;
    __syncthreads();
    for (int off = 1; off < 256; off <<= 1) {
        int u = (t >= off) ? s[t - off] : 0;
        __syncthreads();
        s[t] += u;
        __syncthreads();
    }
    if (i < n) {
        int excl = bstart[b] + s[t] - v;
        row_ptr[i] = excl;
        pos[i] = excl;
        if (i == n - 1) row_ptr[n] = bstart[b] + s[t];
    }
}

__global__ void fill_csr(const int* __restrict__ src, const int* __restrict__ dst,
                         int* __restrict__ pos, int* __restrict__ csr_src, int E) {
    int e = blockIdx.x * blockDim.x + threadIdx.x;
    if (e < E) {
        int p = atomicAdd(&pos[dst[e]], 1);
        csr_src[p] = src[e];
    }
}

__global__ void graph_starts(const int* __restrict__ batch, int* __restrict__ gstart,
                             int n, int G) {
    int g = blockIdx.x * blockDim.x + threadIdx.x;
    if (g > G) return;
    int lo = 0, hi = n;
    while (lo < hi) { int m = (lo + hi) >> 1; if (batch[m] < g) lo = m + 1; else hi = m; }
    gstart[g] = lo;
}

// ---------------- conversions ----------------

__global__ void f32_to_bf16_vec(const float* __restrict__ in,
                                unsigned short* __restrict__ out, int n8) {
    int i = blockIdx.x * blockDim.x + threadIdx.x;
    if (i >= n8) return;
    const float4* in4 = (const float4*)in;
    float4 a = in4[i * 2], b = in4[i * 2 + 1];
    uint4 o;
    o.x = f2bf(a.x) | ((unsigned)f2bf(a.y) << 16);
    o.y = f2bf(a.z) | ((unsigned)f2bf(a.w) << 16);
    o.z = f2bf(b.x) | ((unsigned)f2bf(b.y) << 16);
    o.w = f2bf(b.z) | ((unsigned)f2bf(b.w) << 16);
    ((uint4*)out)[i] = o;
}

// W[mat][k][c] fp32 -> Wt[mat][c][k] bf16
__global__ void transpose_kc(const float* __restrict__ W, unsigned short* __restrict__ Wt,
                             int K, int C, int total) {
    int tid = blockIdx.x * blockDim.x + threadIdx.x;
    if (tid >= total) return;
    int kc = K * C;
    int mat = tid / kc;
    int rem = tid - mat * kc;
    int c = rem / K;
    int k = rem - c * K;
    Wt[tid] = f2bf(W[(size_t)mat * kc + (size_t)k * C + c]);
}

// ---------------- fused GIN layer (gather + MLP), 4-wave, edge-split gather ----------------
// block = 256 thr = 4 waves, 16 node rows.
// Gather: 16 lanes/node = 2 subs x 8 chunk-lanes; sub s walks edges e0+s, e0+s+2,...
//   (2 uint4 chains, unroll 2 -> 4 loads in flight); pair combines via shfl_xor(8).
// GEMM1: wave w computes cols [w*32,w*32+32) from zt; relu -> tt.
// GEMM2: A from tt (K=128); +b2 [,+xres bf16]; emb slice = relu.
template <bool ODD>
__global__ __launch_bounds__(256) void fused_layer(const unsigned short* __restrict__ emb,
                                                   int slice_u4, int row_u4,
                                                   const int* __restrict__ row_ptr,
                                                   const int* __restrict__ csr_src,
                                                   const unsigned short* __restrict__ Wt1,
                                                   const float* __restrict__ b1,
                                                   const unsigned short* __restrict__ Wt2,
                                                   const float* __restrict__ b2,
                                                   unsigned short* __restrict__ xres,
                                                   unsigned short* __restrict__ h_out,
                                                   int out_stride, int N) {
    __shared__ __align__(16) char zt[16 * 256];    // z tile bf16, XOR-swizzled
    __shared__ __align__(16) char tt[16 * 256];    // t tile bf16, XOR-swizzled
    int t = threadIdx.x;
    int rowbase = blockIdx.x * 16;

    // ---- gather (edge-split across sub pairs) ----
    {
        int nl = t >> 4;                 // local node 0..15
        int sub = (t >> 3) & 1;          // edge-parity half
        int lane8 = t & 7;               // chunk lane (chains lane8, lane8+8)
        int node = rowbase + nl;
        const uint4* h4 = (const uint4*)emb;
        float sa0=0,sa1=0,sa2=0,sa3=0,sa4=0,sa5=0,sa6=0,sa7=0;
        float sb0=0,sb1=0,sb2=0,sb3=0,sb4=0,sb5=0,sb6=0,sb7=0;
        if (node < N) {
            if (sub == 0) {
                size_t base = (size_t)node * row_u4 + slice_u4;
                uint4 u0 = h4[base + lane8];
                uint4 u1 = h4[base + lane8 + 8];
                sa0 = bf2f(u0.x & 0xffff); sa1 = bf2f(u0.x >> 16);
                sa2 = bf2f(u0.y & 0xffff); sa3 = bf2f(u0.y >> 16);
                sa4 = bf2f(u0.z & 0xffff); sa5 = bf2f(u0.z >> 16);
                sa6 = bf2f(u0.w & 0xffff); sa7 = bf2f(u0.w >> 16);
                sb0 = bf2f(u1.x & 0xffff); sb1 = bf2f(u1.x >> 16);
                sb2 = bf2f(u1.y & 0xffff); sb3 = bf2f(u1.y >> 16);
                sb4 = bf2f(u1.z & 0xffff); sb5 = bf2f(u1.z >> 16);
                sb6 = bf2f(u1.w & 0xffff); sb7 = bf2f(u1.w >> 16);
            }
            int e0 = row_ptr[node], e1 = row_ptr[node + 1];
            int e = e0 + sub;
            for (; e + 2 < e1; e += 4) {             // this sub's edges, unroll 2
                int i0 = csr_src[e], i1 = csr_src[e + 2];
                size_t p0 = (size_t)i0 * row_u4 + slice_u4;
                size_t p1 = (size_t)i1 * row_u4 + slice_u4;
                uint4 v0 = h4[p0 + lane8];
                uint4 v1 = h4[p0 + lane8 + 8];
                uint4 w0 = h4[p1 + lane8];
                uint4 w1 = h4[p1 + lane8 + 8];
                sa0 += bf2f(v0.x & 0xffff); sa1 += bf2f(v0.x >> 16);
                sa2 += bf2f(v0.y & 0xffff); sa3 += bf2f(v0.y >> 16);
                sa4 += bf2f(v0.z & 0xffff); sa5 += bf2f(v0.z >> 16);
                sa6 += bf2f(v0.w & 0xffff); sa7 += bf2f(v0.w >> 16);
                sb0 += bf2f(v1.x & 0xffff); sb1 += bf2f(v1.x >> 16);
                sb2 += bf2f(v1.y & 0xffff); sb3 += bf2f(v1.y >> 16);
                sb4 += bf2f(v1.z & 0xffff); sb5 += bf2f(v1.z >> 16);
                sb6 += bf2f(v1.w & 0xffff); sb7 += bf2f(v1.w >> 16);
                sa0 += bf2f(w0.x & 0xffff); sa1 += bf2f(w0.x >> 16);
                sa2 += bf2f(w0.y & 0xffff); sa3 += bf2f(w0.y >> 16);
                sa4 += bf2f(w0.z & 0xffff); sa5 += bf2f(w0.z >> 16);
                sa6 += bf2f(w0.w & 0xffff); sa7 += bf2f(w0.w >> 16);
                sb0 += bf2f(w1.x & 0xffff); sb1 += bf2f(w1.x >> 16);
                sb2 += bf2f(w1.y & 0xffff); sb3 += bf2f(w1.y >> 16);
                sb4 += bf2f(w1.z & 0xffff); sb5 += bf2f(w1.z >> 16);
                sb6 += bf2f(w1.w & 0xffff); sb7 += bf2f(w1.w >> 16);
            }
            if (e < e1) {
                size_t p0 = (size_t)csr_src[e] * row_u4 + slice_u4;
                uint4 v0 = h4[p0 + lane8];
                uint4 v1 = h4[p0 + lane8 + 8];
                sa0 += bf2f(v0.x & 0xffff); sa1 += bf2f(v0.x >> 16);
                sa2 += bf2f(v0.y & 0xffff); sa3 += bf2f(v0.y >> 16);
                sa4 += bf2f(v0.z & 0xffff); sa5 += bf2f(v0.z >> 16);
                sa6 += bf2f(v0.w & 0xffff); sa7 += bf2f(v0.w >> 16);
                sb0 += bf2f(v1.x & 0xffff); sb1 += bf2f(v1.x >> 16);
                sb2 += bf2f(v1.y & 0xffff); sb3 += bf2f(v1.y >> 16);
                sb4 += bf2f(v1.z & 0xffff); sb5 += bf2f(v1.z >> 16);
                sb6 += bf2f(v1.w & 0xffff); sb7 += bf2f(v1.w >> 16);
            }
        }
        // pair-combine (t <-> t^8): both subs end with full sums
        sa0 += __shfl_xor(sa0, 8); sa1 += __shfl_xor(sa1, 8);
        sa2 += __shfl_xor(sa2, 8); sa3 += __shfl_xor(sa3, 8);
        sa4 += __shfl_xor(sa4, 8); sa5 += __shfl_xor(sa5, 8);
        sa6 += __shfl_xor(sa6, 8); sa7 += __shfl_xor(sa7, 8);
        sb0 += __shfl_xor(sb0, 8); sb1 += __shfl_xor(sb1, 8);
        sb2 += __shfl_xor(sb2, 8); sb3 += __shfl_xor(sb3, 8);
        sb4 += __shfl_xor(sb4, 8); sb5 += __shfl_xor(sb5, 8);
        sb6 += __shfl_xor(sb6, 8); sb7 += __shfl_xor(sb7, 8);
        // sub0 writes chain lane8 (sa), sub1 writes chain lane8+8 (sb)
        uint4 o;
        if (sub == 0) {
            o.x = f2bf(sa0) | ((unsigned)f2bf(sa1) << 16);
            o.y = f2bf(sa2) | ((unsigned)f2bf(sa3) << 16);
            o.z = f2bf(sa4) | ((unsigned)f2bf(sa5) << 16);
            o.w = f2bf(sa6) | ((unsigned)f2bf(sa7) << 16);
        } else {
            o.x = f2bf(sb0) | ((unsigned)f2bf(sb1) << 16);
            o.y = f2bf(sb2) | ((unsigned)f2bf(sb3) << 16);
            o.z = f2bf(sb4) | ((unsigned)f2bf(sb5) << 16);
            o.w = f2bf(sb6) | ((unsigned)f2bf(sb7) << 16);
        }
        int chunk = lane8 + sub * 8;
        *(uint4*)(zt + nl * 256 + ((chunk * 16) ^ ((nl & 7) << 4))) = o;
    }
    __syncthreads();

    int wave = t >> 6, lane = t & 63, l15 = lane & 15, l4 = lane >> 4;
    int colbase = wave * 32;

    f32x4 acc[2];
#pragma unroll
    for (int ct = 0; ct < 2; ct++) acc[ct] = (f32x4){0.f, 0.f, 0.f, 0.f};

    // ---- GEMM1: A from zt, wave's 32 cols ----
#pragma unroll
    for (int kk = 0; kk < 4; kk++) {
        int k0 = kk * 32 + l4 * 8;
        bf16x8 a0 = *(const bf16x8*)(zt + l15 * 256 + ((k0 * 2) ^ ((l15 & 7) << 4)));
#pragma unroll
        for (int ct = 0; ct < 2; ct++) {
            bf16x8 b = *(const bf16x8*)&Wt1[(size_t)(colbase + ct * 16 + l15) * HID + k0];
            acc[ct] = __builtin_amdgcn_mfma_f32_16x16x32_bf16(a0, b, acc[ct], 0, 0, 0);
        }
    }

    // ---- epilogue1: relu(acc+b1) -> tt ----
#pragma unroll
    for (int ct = 0; ct < 2; ct++) {
        int col = colbase + ct * 16 + l15;
        float bc = b1[col];
#pragma unroll
        for (int j = 0; j < 4; j++) {
            int r = l4 * 4 + j;                     // rows 0..15
            float v = fmaxf(acc[ct][j] + bc, 0.f);
            *(unsigned short*)(tt + r * 256 + ((col * 2) ^ ((r & 7) << 4))) = f2bf(v);
        }
    }
    __syncthreads();

    // ---- GEMM2: A from full tt (K=128), wave's 32 output cols ----
#pragma unroll
    for (int ct = 0; ct < 2; ct++) acc[ct] = (f32x4){0.f, 0.f, 0.f, 0.f};
#pragma unroll
    for (int kk = 0; kk < 4; kk++) {
        int k0 = kk * 32 + l4 * 8;
        bf16x8 a0 = *(const bf16x8*)(tt + l15 * 256 + ((k0 * 2) ^ ((l15 & 7) << 4)));
#pragma unroll
        for (int ct = 0; ct < 2; ct++) {
            bf16x8 b = *(const bf16x8*)&Wt2[(size_t)(colbase + ct * 16 + l15) * HID + k0];
            acc[ct] = __builtin_amdgcn_mfma_f32_16x16x32_bf16(a0, b, acc[ct], 0, 0, 0);
        }
    }

    // ---- epilogue2: +b2 [,+xres bf16], emb slice = relu ----
#pragma unroll
    for (int ct = 0; ct < 2; ct++) {
        int col = colbase + ct * 16 + l15;
        float bc = b2[col];
#pragma unroll
        for (int j = 0; j < 4; j++) {
            int r = l4 * 4 + j;
            int rg = rowbase + r;
            if (rg < N) {
                float v = acc[ct][j] + bc;
                if (ODD) {
                    v += bf2f(xres[(size_t)rg * HID + col]);
                    xres[(size_t)rg * HID + col] = f2bf(v);
                }
                h_out[(size_t)rg * out_stride + col] = f2bf(fmaxf(v, 0.f));
            }
        }
    }
}

// ---------------- pre linear (MFMA, global in, writes emb slice 0 + xres bf16) ----------------
__global__ __launch_bounds__(256) void linear_pre(const unsigned short* __restrict__ in,
                                                  const unsigned short* __restrict__ Wt,
                                                  const float* __restrict__ bias,
                                                  unsigned short* __restrict__ out,
                                                  int out_stride,
                                                  unsigned short* __restrict__ pre_out, int M) {
    int tid = threadIdx.x;
    int wave = tid >> 6, lane = tid & 63;
    int l15 = lane & 15, l4 = lane >> 4;
    int rowbase = blockIdx.x * 64 + wave * 16;
    f32x4 acc[8];
#pragma unroll
    for (int ct = 0; ct < 8; ct++) acc[ct] = (f32x4){0.f, 0.f, 0.f, 0.f};
    int r0 = min(rowbase + l15, M - 1);
#pragma unroll
    for (int kk = 0; kk < 4; kk++) {
        int k0 = kk * 32 + l4 * 8;
        bf16x8 a0 = *(const bf16x8*)&in[(size_t)r0 * HID + k0];
#pragma unroll
        for (int ct = 0; ct < 8; ct++) {
            bf16x8 b = *(const bf16x8*)&Wt[(size_t)(ct * 16 + l15) * HID + k0];
            acc[ct] = __builtin_amdgcn_mfma_f32_16x16x32_bf16(a0, b, acc[ct], 0, 0, 0);
        }
    }
#pragma unroll
    for (int ct = 0; ct < 8; ct++) {
        int col = ct * 16 + l15;
        float bc = bias[col];
#pragma unroll
        for (int j = 0; j < 4; j++) {
            int r = rowbase + l4 * 4 + j;
            if (r < M) {
                float v = acc[ct][j] + bc;
                unsigned short bv = f2bf(v);
                pre_out[(size_t)r * HID + col] = bv;          // xres bf16
                out[(size_t)r * out_stride + col] = bv;       // emb slice 0 (no relu)
            }
        }
    }
}

// ---------------- pooling over full emb, 2-level deterministic ----------------
__global__ __launch_bounds__(128) void pool_all(const unsigned short* __restrict__ emb,
                                                const int* __restrict__ gstart,
                                                float* __restrict__ part, int EMB) {
    int g = blockIdx.x >> 3, sub = blockIdx.x & 7;
    int t = threadIdx.x;
    if (t >= 112) return;
    const uint4* e4 = (const uint4*)emb;     // row stride EMB/8 = 112 uint4
    int row_u4 = EMB / 8;
    int n0 = gstart[g], n1 = gstart[g + 1];
    float s[8] = {0.f, 0.f, 0.f, 0.f, 0.f, 0.f, 0.f, 0.f};
    for (int n = n0 + sub; n < n1; n += 8) {
        uint4 v = e4[(size_t)n * row_u4 + t];
        s[0] += bf2f(v.x & 0xffff); s[1] += bf2f(v.x >> 16);
        s[2] += bf2f(v.y & 0xffff); s[3] += bf2f(v.y >> 16);
        s[4] += bf2f(v.z & 0xffff); s[5] += bf2f(v.z >> 16);
        s[6] += bf2f(v.w & 0xffff); s[7] += bf2f(v.w >> 16);
    }
    float4* p4 = (float4*)&part[(size_t)blockIdx.x * EMB + t * 8];
    p4[0] = (float4){s[0], s[1], s[2], s[3]};
    p4[1] = (float4){s[4], s[5], s[6], s[7]};
}

__global__ __launch_bounds__(128) void pool_fin(const float* __restrict__ part,
                                                unsigned short* __restrict__ pooled,
                                                int EMB) {
    int idx = blockIdx.x * 128 + threadIdx.x;   // over G*EMB
    int g = idx / EMB, c = idx - g * EMB;
    float s = 0.f;
#pragma unroll
    for (int sub = 0; sub < 8; sub++)
        s += part[(size_t)(g * 8 + sub) * EMB + c];
    pooled[idx] = f2bf(s);
}

// ---------------- post MLP via MFMA ----------------
__global__ __launch_bounds__(256) void post_mfma(const unsigned short* __restrict__ pooled,
                                                 const unsigned short* __restrict__ w1t,
                                                 const float* __restrict__ b1,
                                                 const unsigned short* __restrict__ w2t,
                                                 const float* __restrict__ b2,
                                                 float* __restrict__ out, int EMB) {
    __shared__ __align__(16) char lds[128 * 256];
    int t = threadIdx.x;
    int wave = t >> 6, lane = t & 63, l15 = lane & 15, l4 = lane >> 4;
    int wrow = wave * 32;
    f32x4 acc[2][8];
#pragma unroll
    for (int rt = 0; rt < 2; rt++)
#pragma unroll
        for (int ct = 0; ct < 8; ct++) acc[rt][ct] = (f32x4){0.f, 0.f, 0.f, 0.f};
    int r0 = wrow + l15, r1 = r0 + 16;
#pragma unroll 4
    for (int kk = 0; kk < EMB / 32; kk++) {
        int k0 = kk * 32 + l4 * 8;
        bf16x8 a0 = *(const bf16x8*)&pooled[(size_t)r0 * EMB + k0];
        bf16x8 a1 = *(const bf16x8*)&pooled[(size_t)r1 * EMB + k0];
#pragma unroll
        for (int ct = 0; ct < 8; ct++) {
            bf16x8 b = *(const bf16x8*)&w1t[(size_t)(ct * 16 + l15) * EMB + k0];
            acc[0][ct] = __builtin_amdgcn_mfma_f32_16x16x32_bf16(a0, b, acc[0][ct], 0, 0, 0);
            acc[1][ct] = __builtin_amdgcn_mfma_f32_16x16x32_bf16(a1, b, acc[1][ct], 0, 0, 0);
        }
    }
#pragma unroll
    for (int ct = 0; ct < 8; ct++) {
        int col = ct * 16 + l15;
        float bc = b1[col];
#pragma unroll
        for (int rt = 0; rt < 2; rt++)
#pragma unroll
            for (int j = 0; j < 4; j++) {
                int r = wrow + rt * 16 + l4 * 4 + j;
                float v = fmaxf(acc[rt][ct][j] + bc, 0.f);
                *(unsigned short*)(lds + r * 256 + ((col * 2) ^ ((r & 7) << 4))) = f2bf(v);
            }
    }
    __syncthreads();
#pragma unroll
    for (int rt = 0; rt < 2; rt++)
#pragma unroll
        for (int ct = 0; ct < 8; ct++) acc[rt][ct] = (f32x4){0.f, 0.f, 0.f, 0.f};
#pragma unroll
    for (int kk = 0; kk < 4; kk++) {
        int k0 = kk * 32 + l4 * 8;
        bf16x8 a0 = *(const bf16x8*)(lds + r0 * 256 + ((k0 * 2) ^ ((r0 & 7) << 4)));
        bf16x8 a1 = *(const bf16x8*)(lds + r1 * 256 + ((k0 * 2) ^ ((r1 & 7) << 4)));
#pragma unroll
        for (int ct = 0; ct < 8; ct++) {
            bf16x8 b = *(const bf16x8*)&w2t[(size_t)(ct * 16 + l15) * HID + k0];
            acc[0][ct] = __builtin_amdgcn_mfma_f32_16x16x32_bf16(a0, b, acc[0][ct], 0, 0, 0);
            acc[1][ct] = __builtin_amdgcn_mfma_f32_16x16x32_bf16(a1, b, acc[1][ct], 0, 0, 0);
        }
    }
#pragma unroll
    for (int ct = 0; ct < 8; ct++) {
        int col = ct * 16 + l15;
        float bc = b2[col];
#pragma unroll
        for (int rt = 0; rt < 2; rt++)
#pragma unroll
            for (int j = 0; j < 4; j++) {
                int r = wrow + rt * 16 + l4 * 4 + j;
                out[(size_t)r * HID + col] = acc[rt][ct][j] + bc;
            }
    }
}

// ---------------- launch ----------------

extern "C" void kernel_launch(void* const* d_in, const int* in_sizes, int n_in,
                              void* d_out, int out_size, void* d_ws, size_t ws_size,
                              hipStream_t stream) {
    const float* x       = (const float*)d_in[0];
    const int* edge_index= (const int*)d_in[1];
    const int* batch     = (const int*)d_in[2];
    const float* pre_w   = (const float*)d_in[3];
    const float* pre_b   = (const float*)d_in[4];
    const float* conv_w1 = (const float*)d_in[5];
    const float* conv_b1 = (const float*)d_in[6];
    const float* conv_w2 = (const float*)d_in[7];
    const float* conv_b2 = (const float*)d_in[8];
    const float* post_w1 = (const float*)d_in[9];
    const float* post_b1 = (const float*)d_in[10];
    const float* post_w2 = (const float*)d_in[11];
    const float* post_b2 = (const float*)d_in[12];
    float* outp = (float*)d_out;

    int N = in_sizes[0] / HID;
    int E = in_sizes[1] / 2;
    int L = in_sizes[5] / (HID * HID);
    int G = out_size / HID;
    int EMB = (L + 1) * HID;

    const int* src = edge_index;
    const int* dst = edge_index + E;

    char* w = (char*)d_ws;
    auto alloc = [&](size_t bytes) -> char* {
        char* p = w;
        w += (bytes + 255) & ~(size_t)255;
        return p;
    };
    unsigned short* emb   = (unsigned short*)alloc((size_t)N * EMB * 2);     // all layer embeddings
    unsigned short* x_bf  = (unsigned short*)alloc((size_t)N * HID * 2);
    unsigned short* xres  = (unsigned short*)alloc((size_t)N * HID * 2);     // bf16 residual
    float* part   = (float*)alloc((size_t)G * 8 * EMB * 4);
    unsigned short* pooled = (unsigned short*)alloc((size_t)G * EMB * 2);
    unsigned short* Wt_pre = (unsigned short*)alloc((size_t)HID * HID * 2);
    unsigned short* Wt_c1  = (unsigned short*)alloc((size_t)L * HID * HID * 2);
    unsigned short* Wt_c2  = (unsigned short*)alloc((size_t)L * HID * HID * 2);
    unsigned short* w1t    = (unsigned short*)alloc((size_t)EMB * HID * 2);
    unsigned short* w2t    = (unsigned short*)alloc((size_t)HID * HID * 2);
    int* deg      = (int*)alloc((size_t)(N + 1) * 4);
    int* row_ptr  = (int*)alloc((size_t)(N + 1) * 4);
    int* pos      = (int*)alloc((size_t)(N + 1) * 4);
    int* bsum     = (int*)alloc((size_t)1024 * 4);
    int* bstart   = (int*)alloc((size_t)1024 * 4);
    int* csr_src  = (int*)alloc((size_t)E * 4);
    int* gstart   = (int*)alloc((size_t)(G + 1) * 4);
    (void)ws_size; (void)n_in;

    int eb = (E + 255) / 256;
    int nb = (N + 255) / 256;

    // CSR by dst
    zero_i32<<<nb, 256, 0, stream>>>(deg, N);
    count_deg<<<eb, 256, 0, stream>>>(dst, deg, E);
    block_sums<<<nb, 256, 0, stream>>>(deg, bsum, N);
    scan_bsums<<<1, 1024, 0, stream>>>(bsum, bstart, nb);
    scan_within<<<nb, 256, 0, stream>>>(deg, bstart, row_ptr, pos, N);
    fill_csr<<<eb, 256, 0, stream>>>(src, dst, pos, csr_src, E);
    graph_starts<<<1, 256, 0, stream>>>(batch, gstart, N, G);

    // conversions / transposes
    f32_to_bf16_vec<<<(N * HID / 8 + 255) / 256, 256, 0, stream>>>(x, x_bf, N * HID / 8);
    transpose_kc<<<(HID * HID + 255) / 256, 256, 0, stream>>>(pre_w, Wt_pre, HID, HID, HID * HID);
    transpose_kc<<<(L * HID * HID + 255) / 256, 256, 0, stream>>>(conv_w1, Wt_c1, HID, HID, L * HID * HID);
    transpose_kc<<<(L * HID * HID + 255) / 256, 256, 0, stream>>>(conv_w2, Wt_c2, HID, HID, L * HID * HID);
    transpose_kc<<<(EMB * HID + 255) / 256, 256, 0, stream>>>(post_w1, w1t, EMB, HID, EMB * HID);
    transpose_kc<<<(HID * HID + 255) / 256, 256, 0, stream>>>(post_w2, w2t, HID, HID, HID * HID);

    int gb64 = (N + 63) / 64;
    int gb16 = (N + 15) / 16;

    // pre linear: emb slice0 = x@pre_w + pre_b (no relu) ; xres = same (bf16)
    linear_pre<<<gb64, 256, 0, stream>>>(x_bf, Wt_pre, pre_b, emb, EMB, xres, N);

    for (int i = 0; i < L; i++) {
        unsigned short* slice_out = emb + (size_t)(i + 1) * HID;
        if (i & 1) {
            fused_layer<true><<<gb16, 256, 0, stream>>>(
                emb, i * 16, EMB / 8, row_ptr, csr_src,
                Wt_c1 + (size_t)i * HID * HID, conv_b1 + i * HID,
                Wt_c2 + (size_t)i * HID * HID, conv_b2 + i * HID,
                xres, slice_out, EMB, N);
        } else {
            fused_layer<false><<<gb16, 256, 0, stream>>>(
                emb, i * 16, EMB / 8, row_ptr, csr_src,
                Wt_c1 + (size_t)i * HID * HID, conv_b1 + i * HID,
                Wt_c2 + (size_t)i * HID * HID, conv_b2 + i * HID,
                xres, slice_out, EMB, N);
        }
    }

    pool_all<<<G * 8, 128, 0, stream>>>(emb, gstart, part, EMB);
    pool_fin<<<(G * EMB) / 128, 128, 0, stream>>>(part, pooled, EMB);
    post_mfma<<<1, 256, 0, stream>>>(pooled, w1t, post_b1, w2t, post_b2, outp, EMB);
}